// Round 11
// baseline (3995.350 us; speedup 1.0000x reference)
//
#include <hip/hip_runtime.h>
#include <hip/hip_bf16.h>
#include <math.h>

#define BB 8
#define NN 8192
#define SS 2048
#define NSAMP 32

typedef unsigned long long u64;

// K0: transpose xyz (B,3,N) f32 -> X (B,N,3) f32
__global__ void k_transpose(const float* __restrict__ xyz, float* __restrict__ X) {
    int e = blockIdx.x * 256 + threadIdx.x;
    if (e >= BB * 3 * NN) return;
    int n = e % NN;
    int bc = e / NN;
    int c = bc % 3;
    int b = bc / 3;
    X[((size_t)(b * NN + n)) * 3 + c] = xyz[e];
}

// K1: farthest point sampling, one block per batch.
// ARITHMETIC FROZEN (bit-exact vs reference, r18 PASS). r26 structure
// (VERIFIED r27/r29/r30: ~1990 us, VGPR 88, VALU-issue-bound on 8 CUs).
// UNCHANGED (control).
__device__ __forceinline__ u64 fps_wave_max(u64 key) {
#define FPS_DPP_STAGE(CTRL)                                                   \
    {                                                                         \
        int lo = (int)(unsigned)(key & 0xffffffffull);                        \
        int hi = (int)(unsigned)(key >> 32);                                  \
        int lo2 = __builtin_amdgcn_update_dpp(lo, lo, CTRL, 0xF, 0xF, false); \
        int hi2 = __builtin_amdgcn_update_dpp(hi, hi, CTRL, 0xF, 0xF, false); \
        u64 k2 = ((u64)(unsigned)hi2 << 32) | (unsigned)lo2;                  \
        if (k2 > key) key = k2;                                               \
    }
    FPS_DPP_STAGE(0x121)  // row_ror:1
    FPS_DPP_STAGE(0x122)  // row_ror:2
    FPS_DPP_STAGE(0x124)  // row_ror:4
    FPS_DPP_STAGE(0x128)  // row_ror:8
    FPS_DPP_STAGE(0x142)  // row_bcast15
    FPS_DPP_STAGE(0x143)  // row_bcast31
#undef FPS_DPP_STAGE
    return key;  // lane 63 holds the full wave max
}

__global__ __launch_bounds__(512)
__attribute__((amdgpu_waves_per_eu(2, 2))) void k_fps(
    const float* __restrict__ X, float* __restrict__ NXYZ) {
    __shared__ float lx[NN], ly[NN], lz[NN];  // 96 KB winner-broadcast cache
    __shared__ float nbuf[SS * 3];            // 24 KB result buffer
    __shared__ u64 wk_[2][8];
    int b = blockIdx.x;
    int tid = threadIdx.x;
    const float* xb = X + (size_t)b * NN * 3;
    float px[16], py[16], pz[16], dist[16];
#pragma unroll
    for (int i = 0; i < 16; ++i) {
        int n = tid + (i << 9);
        px[i] = xb[(size_t)n * 3 + 0];
        py[i] = xb[(size_t)n * 3 + 1];
        pz[i] = xb[(size_t)n * 3 + 2];
        dist[i] = 1e10f;
        lx[n] = px[i]; ly[n] = py[i]; lz[n] = pz[i];
    }
#pragma unroll
    for (int i = 0; i < 16; ++i) {
        asm volatile("" : "+v"(px[i]), "+v"(py[i]), "+v"(pz[i]));
    }
    float c0 = xb[0], c1 = xb[1], c2 = xb[2];
    int lane = tid & 63, wv = tid >> 6;
    __syncthreads();
    for (int t = 0; t < SS; ++t) {
        if (tid == 0) {
            nbuf[t * 3 + 0] = c0; nbuf[t * 3 + 1] = c1; nbuf[t * 3 + 2] = c2;
        }
        float bv0 = -1.0f, bv1 = -1.0f, bv2 = -1.0f, bv3 = -1.0f;
        int bn0 = 0, bn1 = 0, bn2 = 0, bn3 = 0;
#pragma unroll
        for (int i = 0; i < 16; ++i) {
            float dx = __fsub_rn(px[i], c0);
            float dy = __fsub_rn(py[i], c1);
            float dz = __fsub_rn(pz[i], c2);
            float dd = __fadd_rn(__fadd_rn(__fmul_rn(dx, dx), __fmul_rn(dy, dy)),
                                 __fmul_rn(dz, dz));
            float nd = fminf(dist[i], dd);
            dist[i] = nd;
            int n = tid + (i << 9);
            if (i < 4) {
                if (nd > bv0) { bv0 = nd; bn0 = n; }
            } else if (i < 8) {
                if (nd > bv1) { bv1 = nd; bn1 = n; }
            } else if (i < 12) {
                if (nd > bv2) { bv2 = nd; bn2 = n; }
            } else {
                if (nd > bv3) { bv3 = nd; bn3 = n; }
            }
        }
        float bestv = bv0; int bestn = bn0;
        if (bv1 > bestv) { bestv = bv1; bestn = bn1; }
        if (bv2 > bestv) { bestv = bv2; bestn = bn2; }
        if (bv3 > bestv) { bestv = bv3; bestn = bn3; }
        u64 key = ((u64)__float_as_uint(bestv) << 32) | (unsigned)(~bestn);
        key = fps_wave_max(key);
        int pbuf = t & 1;
        if (lane == 63) wk_[pbuf][wv] = key;
        __syncthreads();
        u64 kmax = wk_[pbuf][0];
#pragma unroll
        for (int i = 1; i < 8; ++i) {
            u64 k = wk_[pbuf][i];
            if (k > kmax) kmax = k;
        }
        int kn = (int)(~(unsigned)(kmax & 0xffffffffull));
        c0 = lx[kn]; c1 = ly[kn]; c2 = lz[kn];
    }
    __syncthreads();
    float* ob = NXYZ + (size_t)b * SS * 3;
    for (int e = tid; e < SS * 3; e += 512) ob[e] = nbuf[e];
}

// K2: ball query. One wave per center. ARITHMETIC FROZEN (r18 PASS).
__global__ __launch_bounds__(256) void k_ballq(const float* __restrict__ X,
                                               const float* __restrict__ NXYZ,
                                               int* __restrict__ GI) {
    int wv = threadIdx.x >> 6, lane = threadIdx.x & 63;
    int gs = blockIdx.x * 4 + wv;           // 0..16383
    int b = gs >> 11;
    const float* xb = X + (size_t)b * NN * 3;
    float c0 = NXYZ[(size_t)gs * 3 + 0];
    float c1 = NXYZ[(size_t)gs * 3 + 1];
    float c2 = NXYZ[(size_t)gs * 3 + 2];
    float A = __fadd_rn(__fadd_rn(__fmul_rn(c0, c0), __fmul_rn(c1, c1)),
                        __fmul_rn(c2, c2));
    const float R2 = 0.04f;
    int cnt = 0, first = 0;
    int* gout = GI + ((size_t)gs << 5);
    for (int r = 0; r < 128 && cnt < 32; ++r) {
        int n = (r << 6) + lane;
        float x0 = xb[(size_t)n * 3 + 0];
        float x1 = xb[(size_t)n * 3 + 1];
        float x2 = xb[(size_t)n * 3 + 2];
        float Bx = __fadd_rn(__fadd_rn(__fmul_rn(x0, x0), __fmul_rn(x1, x1)),
                             __fmul_rn(x2, x2));
        float dot = fmaf(c2, x2, fmaf(c1, x1, __fmul_rn(c0, x0)));  // BLAS asc-FMA
        float t = __fadd_rn(__fmul_rn(-2.0f, dot), Bx);             // += B first
        float sqr = __fadd_rn(t, A);                                // += A second
        bool pred = !(sqr > R2);
        u64 mask = __ballot(pred);
        int rank = cnt + __popcll(mask & ((1ull << lane) - 1ull));
        if (pred && rank < 32) gout[rank] = n;
        if (cnt == 0 && mask) first = (r << 6) + (__ffsll((long long)mask) - 1);
        cnt += __popcll(mask);
    }
    if (cnt < 32 && lane >= cnt && lane < 32) gout[lane] = first;
}

// K3: build group features in LDS + attention block 1 + maxpool.
// r30 b128 version (NEUTRAL vs r29 — GEMMs weren't the critical path;
// gather-latency suspected). UNCHANGED this round (control).
__global__ __launch_bounds__(256) void k_attn1(
    const float* __restrict__ X, const float* __restrict__ NXYZ,
    const int* __restrict__ GI, const float* __restrict__ P,
    const float* __restrict__ wq, const float* __restrict__ wk,
    const float* __restrict__ wv, const float* __restrict__ wo,
    const float* __restrict__ wp, const float* __restrict__ bp,
    float* __restrict__ FMID) {
    __shared__ float feat[32][68], qS[32][68], kS[32][68], vS[32][68];
    __shared__ float sc[32][36];
    __shared__ float pos[32][3];
    __shared__ int giS[32];
    __shared__ float ctr[3];
    int gs = blockIdx.x;
    int b = gs >> 11;
    int tid = threadIdx.x;
    if (tid < 32) giS[tid] = GI[((size_t)gs << 5) + tid];
    if (tid < 3) ctr[tid] = NXYZ[(size_t)gs * 3 + tid];
    __syncthreads();
    const float* xb = X + (size_t)b * NN * 3;
    const float* pb = P + (size_t)b * 61 * NN;
    int d = tid & 63, g4 = tid >> 6;
    for (int jj = 0; jj < 8; ++jj) {
        int j = g4 * 8 + jj;
        int idx = giS[j];
        float val;
        if (d < 3) {
            float xv = xb[(size_t)idx * 3 + d];
            pos[j][d] = xv;
            val = __fsub_rn(xv, ctr[d]);
        } else {
            val = pb[(size_t)(d - 3) * NN + idx];
        }
        feat[j][d] = val;
    }
    __syncthreads();
    float aq[8], ak[8], av[8];
#pragma unroll
    for (int i = 0; i < 8; ++i) { aq[i] = 0.f; ak[i] = 0.f; av[i] = 0.f; }
    for (int kk4 = 0; kk4 < 16; ++kk4) {
        float4 f4[8];
#pragma unroll
        for (int i = 0; i < 8; ++i)
            f4[i] = *(const float4*)&feat[g4 + 4 * i][kk4 * 4];
#pragma unroll
        for (int j = 0; j < 4; ++j) {
            int kk = kk4 * 4 + j;
            float wqv = wq[kk * 64 + d];
            float wkv = wk[kk * 64 + d];
            float wvv = wv[kk * 64 + d];
#pragma unroll
            for (int i = 0; i < 8; ++i) {
                float f = (j == 0) ? f4[i].x : (j == 1) ? f4[i].y
                                  : (j == 2) ? f4[i].z : f4[i].w;
                aq[i] = fmaf(f, wqv, aq[i]);
                ak[i] = fmaf(f, wkv, ak[i]);
                av[i] = fmaf(f, wvv, av[i]);
            }
        }
    }
    {
        float wp0 = wp[d], wp1 = wp[64 + d], wp2 = wp[128 + d];
        float bpd = bp[d];
#pragma unroll
        for (int i = 0; i < 8; ++i) {
            int j = g4 + 4 * i;
            float pterm = fmaf(pos[j][2], wp2, fmaf(pos[j][1], wp1, pos[j][0] * wp0)) + bpd;
            av[i] += pterm;
            qS[j][d] = aq[i]; kS[j][d] = ak[i]; vS[j][d] = av[i];
        }
    }
    __syncthreads();
    for (int e = tid; e < 1024; e += 256) {
        int r = e >> 5, ci = e & 31;
        float acc = 0.f;
#pragma unroll
        for (int k4 = 0; k4 < 16; ++k4) {
            float4 q4 = *(const float4*)&qS[r][k4 * 4];
            float4 kv4 = *(const float4*)&kS[ci][k4 * 4];
            acc = fmaf(q4.x, kv4.x, acc);
            acc = fmaf(q4.y, kv4.y, acc);
            acc = fmaf(q4.z, kv4.z, acc);
            acc = fmaf(q4.w, kv4.w, acc);
        }
        sc[r][ci] = acc * 0.125f;
    }
    __syncthreads();
    if (tid < 32) {
        float m = -INFINITY;
        for (int i2 = 0; i2 < 32; ++i2) m = fmaxf(m, sc[tid][i2]);
        float sum = 0.f;
        for (int i2 = 0; i2 < 32; ++i2) {
            float e2 = expf(sc[tid][i2] - m);
            sc[tid][i2] = e2; sum += e2;
        }
        float inv = 1.0f / sum;
        for (int i2 = 0; i2 < 32; ++i2) sc[tid][i2] *= inv;
    }
    __syncthreads();
    for (int e = tid; e < 2048; e += 256) {
        int j = e >> 6, dd2 = e & 63;
        float acc = 0.f;
#pragma unroll
        for (int s4 = 0; s4 < 8; ++s4) {
            float4 p4 = *(const float4*)&sc[j][s4 * 4];
            acc = fmaf(p4.x, vS[s4 * 4 + 0][dd2], acc);
            acc = fmaf(p4.y, vS[s4 * 4 + 1][dd2], acc);
            acc = fmaf(p4.z, vS[s4 * 4 + 2][dd2], acc);
            acc = fmaf(p4.w, vS[s4 * 4 + 3][dd2], acc);
        }
        qS[j][dd2] = acc;
    }
    __syncthreads();
    float o[8];
#pragma unroll
    for (int i = 0; i < 8; ++i) o[i] = feat[g4 + 4 * i][d];
    for (int kk4 = 0; kk4 < 16; ++kk4) {
        float4 a4[8];
#pragma unroll
        for (int i = 0; i < 8; ++i)
            a4[i] = *(const float4*)&qS[g4 + 4 * i][kk4 * 4];
#pragma unroll
        for (int j = 0; j < 4; ++j) {
            int kk = kk4 * 4 + j;
            float wov = wo[kk * 64 + d];
#pragma unroll
            for (int i = 0; i < 8; ++i) {
                float a = (j == 0) ? a4[i].x : (j == 1) ? a4[i].y
                                  : (j == 2) ? a4[i].z : a4[i].w;
                o[i] = fmaf(a, wov, o[i]);
            }
        }
    }
    float pm = o[0];
#pragma unroll
    for (int i = 1; i < 8; ++i) pm = fmaxf(pm, o[i]);
    __syncthreads();
    feat[g4][d] = pm;
    __syncthreads();
    if (tid < 64) {
        float mm = fmaxf(fmaxf(feat[0][tid], feat[1][tid]),
                         fmaxf(feat[2][tid], feat[3][tid]));
        FMID[((size_t)gs << 6) + tid] = mm;
    }
}

// K4: q/k/v projections for attention block 2 (rows = B*2048)
__global__ __launch_bounds__(256) void k_qkv2(
    const float* __restrict__ FMID, const float* __restrict__ NXYZ,
    const float* __restrict__ wq, const float* __restrict__ wk,
    const float* __restrict__ wv, const float* __restrict__ wp,
    const float* __restrict__ bpv,
    float* __restrict__ Q2, float* __restrict__ K2, float* __restrict__ V2) {
    __shared__ float f[4][65];
    int tid = threadIdx.x;
    int lr = tid >> 6, d = tid & 63;
    size_t row = (size_t)blockIdx.x * 4 + lr;
    f[lr][d] = FMID[row * 64 + d];
    __syncthreads();
    float aq = 0.f, ak = 0.f, av = 0.f;
    for (int kk = 0; kk < 64; ++kk) {
        float fv = f[lr][kk];
        aq = fmaf(fv, wq[kk * 64 + d], aq);
        ak = fmaf(fv, wk[kk * 64 + d], ak);
        av = fmaf(fv, wv[kk * 64 + d], av);
    }
    float p0 = NXYZ[row * 3], p1 = NXYZ[row * 3 + 1], p2 = NXYZ[row * 3 + 2];
    av += fmaf(p2, wp[128 + d], fmaf(p1, wp[64 + d], p0 * wp[d])) + bpv[d];
    Q2[row * 64 + d] = aq; K2[row * 64 + d] = ak; V2[row * 64 + d] = av;
}

// K5: attention block 2, flash-style online softmax. 16 Q-rows per block.
// r31: kill PV's DS-instruction sink. Per (rr,tile) PV was 64 ds_bpermute
// (shfl pj) + 64 scalar vT column reads = 128 DS wave-instr; x4rr x32tiles
// x4waves ~ 65K DS instr/block ~ 1.5M DS cyc/CU => ~550us of the rest.
// Fixes (composing r28's idea with r29's conflict lessons):
//  - vTT[d][j] (stride 68) staged with mapping r=e&63, c4=e>>6: scalar
//    writes hit banks (const+lane) mod 32 = 2-way = FREE (r28's 8-way came
//    from the r=e>>4 mapping). PV reads = 16 b128 of lane's own row,
//    BW-minimal (same 68-stride pattern as the verified QK reads).
//  - P via per-wave pS[4][64] (1 KB, wave-private; in-wave lgkmcnt orders
//    write->read, no barrier): 1 ds_write + 16 b128 broadcasts replaces 64
//    bpermutes. Same for the epilogue's 64 shfl(avl).
//  PV: 128 -> 33 DS instr per (rr,tile); all values bit-copies, all fma
//  chains keep identical ascending j/kk order => bit-identical results.
// LDS = 17408(kT) + 17408(vTT) + 4096(qSh) + 1024(pS) = 39936 <= 40960
// => 4 blocks/CU KEPT (r28 lesson, checked).
__global__ __launch_bounds__(256) void k_attn2(
    const float* __restrict__ Q2, const float* __restrict__ K2,
    const float* __restrict__ V2, const float* __restrict__ FMID,
    const float* __restrict__ wo, float* __restrict__ out1) {
    __shared__ float kT[64][68];   // K tile, row-major, 272B rows
    __shared__ float vTT[64][68];  // vTT[d][j] = V[j][d]
    __shared__ float qSh[16][64];
    __shared__ float pS[4][64];    // per-wave P/avl row buffer
    int tid = threadIdx.x;
    int wv = tid >> 6, lane = tid & 63;
    int b = blockIdx.x >> 7, rb = blockIdx.x & 127;
    size_t rbase = (size_t)b * SS + rb * 16;
    {
        int r = tid >> 4, d4 = tid & 15;  // 256 threads = 16 rows x 16 quads
        *(float4*)&qSh[r][d4 * 4] =
            *(const float4*)&Q2[(rbase + (size_t)r) * 64 + d4 * 4];
    }
    float acc[4] = {0.f, 0.f, 0.f, 0.f};
    float mr[4] = {-INFINITY, -INFINITY, -INFINITY, -INFINITY};
    float lr[4] = {0.f, 0.f, 0.f, 0.f};
    for (int tt = 0; tt < 32; ++tt) {
        __syncthreads();
        for (int e = tid; e < 1024; e += 256) {
            // K: row-major b128 (conflict-free, verified r29)
            int r1 = e >> 4, d4 = e & 15;
            size_t srcK = ((size_t)b * SS + tt * 64 + r1) * 64 + d4 * 4;
            *(float4*)&kT[r1][d4 * 4] = *(const float4*)&K2[srcK];
            // V: transposed store, conflict-free mapping (lane = source row)
            int r2 = e & 63, c4 = e >> 6;
            size_t srcV = ((size_t)b * SS + tt * 64 + r2) * 64 + c4 * 4;
            float4 vv = *(const float4*)&V2[srcV];
            vTT[c4 * 4 + 0][r2] = vv.x;
            vTT[c4 * 4 + 1][r2] = vv.y;
            vTT[c4 * 4 + 2][r2] = vv.z;
            vTT[c4 * 4 + 3][r2] = vv.w;
        }
        __syncthreads();
#pragma unroll
        for (int rr = 0; rr < 4; ++rr) {
            int lrow = wv * 4 + rr;
            // QK: lane = key; q broadcast + own-row b128 (ascending dd).
            float sj = 0.f;
#pragma unroll
            for (int d4 = 0; d4 < 16; ++d4) {
                float4 q4 = *(const float4*)&qSh[lrow][d4 * 4];
                float4 k4 = *(const float4*)&kT[lane][d4 * 4];
                sj = fmaf(q4.x, k4.x, sj);
                sj = fmaf(q4.y, k4.y, sj);
                sj = fmaf(q4.z, k4.z, sj);
                sj = fmaf(q4.w, k4.w, sj);
            }
            sj *= 0.125f;
            float tm = sj;
#pragma unroll
            for (int off = 32; off > 0; off >>= 1)
                tm = fmaxf(tm, __shfl_down(tm, (unsigned)off, 64));
            tm = __shfl(tm, 0, 64);
            float mnew = fmaxf(mr[rr], tm);
            float alpha = expf(mr[rr] - mnew);
            float pj = expf(sj - mnew);
            float ps = pj;
#pragma unroll
            for (int off = 32; off > 0; off >>= 1) ps += __shfl_down(ps, (unsigned)off, 64);
            ps = __shfl(ps, 0, 64);
            lr[rr] = lr[rr] * alpha + ps;
            // PV: publish P row to wave-private LDS (bit-copy), then lane =
            // output dim reads its own contiguous vTT row. Ascending j chain.
            pS[wv][lane] = pj;
            float a2 = acc[rr] * alpha;
#pragma unroll
            for (int j4 = 0; j4 < 16; ++j4) {
                float4 p4 = *(const float4*)&pS[wv][j4 * 4];
                float4 v4 = *(const float4*)&vTT[lane][j4 * 4];
                a2 = fmaf(p4.x, v4.x, a2);
                a2 = fmaf(p4.y, v4.y, a2);
                a2 = fmaf(p4.z, v4.z, a2);
                a2 = fmaf(p4.w, v4.w, a2);
            }
            acc[rr] = a2;
            mr[rr] = mnew;
        }
    }
#pragma unroll
    for (int rr = 0; rr < 4; ++rr) {
        int lrow = wv * 4 + rr;
        size_t row = rbase + lrow;
        float avl = acc[rr] / lr[rr];
        // out-proj: avl row via wave-private LDS instead of 64 shfl.
        pS[wv][lane] = avl;
        float o = FMID[row * 64 + lane];
#pragma unroll
        for (int k4 = 0; k4 < 16; ++k4) {
            float4 a4 = *(const float4*)&pS[wv][k4 * 4];
            o = fmaf(a4.x, wo[(k4 * 4 + 0) * 64 + lane], o);
            o = fmaf(a4.y, wo[(k4 * 4 + 1) * 64 + lane], o);
            o = fmaf(a4.z, wo[(k4 * 4 + 2) * 64 + lane], o);
            o = fmaf(a4.w, wo[(k4 * 4 + 3) * 64 + lane], o);
        }
        out1[((size_t)b * 64 + lane) * SS + (size_t)(rb * 16 + lrow)] = o;
    }
}

// K6: new_xyz (B,S,3) f32 -> out0 (B,3,S) f32
__global__ void k_out0(const float* __restrict__ NXYZ, float* __restrict__ out0) {
    int e = blockIdx.x * 256 + threadIdx.x;
    if (e >= BB * 3 * SS) return;
    int s = e % SS;
    int bc = e / SS;
    int c = bc % 3;
    int b = bc / 3;
    out0[e] = NXYZ[((size_t)b * SS + s) * 3 + c];
}

extern "C" void kernel_launch(void* const* d_in, const int* in_sizes, int n_in,
                              void* d_out, int out_size, void* d_ws, size_t ws_size,
                              hipStream_t stream) {
    const float* xyz = (const float*)d_in[0];
    const float* pts = (const float*)d_in[1];
    const float* w1q = (const float*)d_in[2];
    const float* w1k = (const float*)d_in[3];
    const float* w1v = (const float*)d_in[4];
    const float* w1o = (const float*)d_in[5];
    const float* w1p = (const float*)d_in[6];
    const float* b1p = (const float*)d_in[7];
    const float* w2q = (const float*)d_in[8];
    const float* w2k = (const float*)d_in[9];
    const float* w2v = (const float*)d_in[10];
    const float* w2o = (const float*)d_in[11];
    const float* w2p = (const float*)d_in[12];
    const float* b2p = (const float*)d_in[13];

    float* X = (float*)d_ws;                               // B*N*3
    float* NXYZ = X + (size_t)BB * NN * 3;                 // B*S*3
    int* GI = (int*)(NXYZ + (size_t)BB * SS * 3);          // B*S*32
    float* FMID = (float*)(GI + (size_t)BB * SS * 32);     // B*S*64
    float* Q2 = FMID + (size_t)BB * SS * 64;
    float* K2 = Q2 + (size_t)BB * SS * 64;
    float* V2 = K2 + (size_t)BB * SS * 64;

    float* out0 = (float*)d_out;
    float* out1 = out0 + (size_t)BB * 3 * SS;

    k_transpose<<<768, 256, 0, stream>>>(xyz, X);
    k_fps<<<BB, 512, 0, stream>>>(X, NXYZ);
    k_ballq<<<4096, 256, 0, stream>>>(X, NXYZ, GI);
    k_attn1<<<16384, 256, 0, stream>>>(X, NXYZ, GI, pts, w1q, w1k, w1v, w1o,
                                       w1p, b1p, FMID);
    k_qkv2<<<4096, 256, 0, stream>>>(FMID, NXYZ, w2q, w2k, w2v, w2p, b2p,
                                     Q2, K2, V2);
    k_attn2<<<1024, 256, 0, stream>>>(Q2, K2, V2, FMID, w2o, out1);
    k_out0<<<192, 256, 0, stream>>>(NXYZ, out0);
}

// Round 12
// 3390.319 us; speedup vs baseline: 1.1785x; 1.1785x over previous
//
#include <hip/hip_runtime.h>
#include <hip/hip_bf16.h>
#include <math.h>

#define BB 8
#define NN 8192
#define SS 2048
#define NSAMP 32

typedef unsigned long long u64;

// K0: transpose xyz (B,3,N) f32 -> X (B,N,3) f32
__global__ void k_transpose(const float* __restrict__ xyz, float* __restrict__ X) {
    int e = blockIdx.x * 256 + threadIdx.x;
    if (e >= BB * 3 * NN) return;
    int n = e % NN;
    int bc = e / NN;
    int c = bc % 3;
    int b = bc / 3;
    X[((size_t)(b * NN + n)) * 3 + c] = xyz[e];
}

// K0b (r32): transpose P (B,61,N) -> PT (B,N,61) via LDS tile, so attn1's
// gather reads 61 CONSECUTIVE floats per point (~4-5 cache lines) instead of
// 61 scattered columns (61 lines). Bit-copy only.
__global__ __launch_bounds__(256) void k_transP(const float* __restrict__ P,
                                                float* __restrict__ PT) {
    __shared__ float tile[61][65];
    int blk = blockIdx.x;           // b*128 + chunk
    int b = blk >> 7, chunk = blk & 127;
    int n0 = chunk * 64;
    const float* pb = P + (size_t)b * 61 * NN;
    int tid = threadIdx.x;
    for (int e = tid; e < 61 * 64; e += 256) {
        int c = e >> 6, n = e & 63;     // coalesced 64-float runs per row c
        tile[c][n] = pb[(size_t)c * NN + n0 + n];
    }
    __syncthreads();
    float* out = PT + ((size_t)b * NN + n0) * 61;
    for (int e = tid; e < 61 * 64; e += 256) {
        int n = e / 61, c = e % 61;     // consecutive e -> consecutive out addr
        out[e] = tile[c][n];            // LDS banks (65c+n)%32 distinct: free
    }
}

// K1: farthest point sampling, one block per batch.
// ARITHMETIC FROZEN (bit-exact vs reference, r18 PASS). r26 structure
// (VERIFIED r27-r31: ~1990 us, VGPR 88, VALU-issue-bound on 8 CUs).
// UNCHANGED (control).
__device__ __forceinline__ u64 fps_wave_max(u64 key) {
#define FPS_DPP_STAGE(CTRL)                                                   \
    {                                                                         \
        int lo = (int)(unsigned)(key & 0xffffffffull);                        \
        int hi = (int)(unsigned)(key >> 32);                                  \
        int lo2 = __builtin_amdgcn_update_dpp(lo, lo, CTRL, 0xF, 0xF, false); \
        int hi2 = __builtin_amdgcn_update_dpp(hi, hi, CTRL, 0xF, 0xF, false); \
        u64 k2 = ((u64)(unsigned)hi2 << 32) | (unsigned)lo2;                  \
        if (k2 > key) key = k2;                                               \
    }
    FPS_DPP_STAGE(0x121)  // row_ror:1
    FPS_DPP_STAGE(0x122)  // row_ror:2
    FPS_DPP_STAGE(0x124)  // row_ror:4
    FPS_DPP_STAGE(0x128)  // row_ror:8
    FPS_DPP_STAGE(0x142)  // row_bcast15
    FPS_DPP_STAGE(0x143)  // row_bcast31
#undef FPS_DPP_STAGE
    return key;  // lane 63 holds the full wave max
}

__global__ __launch_bounds__(512)
__attribute__((amdgpu_waves_per_eu(2, 2))) void k_fps(
    const float* __restrict__ X, float* __restrict__ NXYZ) {
    __shared__ float lx[NN], ly[NN], lz[NN];  // 96 KB winner-broadcast cache
    __shared__ float nbuf[SS * 3];            // 24 KB result buffer
    __shared__ u64 wk_[2][8];
    int b = blockIdx.x;
    int tid = threadIdx.x;
    const float* xb = X + (size_t)b * NN * 3;
    float px[16], py[16], pz[16], dist[16];
#pragma unroll
    for (int i = 0; i < 16; ++i) {
        int n = tid + (i << 9);
        px[i] = xb[(size_t)n * 3 + 0];
        py[i] = xb[(size_t)n * 3 + 1];
        pz[i] = xb[(size_t)n * 3 + 2];
        dist[i] = 1e10f;
        lx[n] = px[i]; ly[n] = py[i]; lz[n] = pz[i];
    }
#pragma unroll
    for (int i = 0; i < 16; ++i) {
        asm volatile("" : "+v"(px[i]), "+v"(py[i]), "+v"(pz[i]));
    }
    float c0 = xb[0], c1 = xb[1], c2 = xb[2];
    int lane = tid & 63, wv = tid >> 6;
    __syncthreads();
    for (int t = 0; t < SS; ++t) {
        if (tid == 0) {
            nbuf[t * 3 + 0] = c0; nbuf[t * 3 + 1] = c1; nbuf[t * 3 + 2] = c2;
        }
        float bv0 = -1.0f, bv1 = -1.0f, bv2 = -1.0f, bv3 = -1.0f;
        int bn0 = 0, bn1 = 0, bn2 = 0, bn3 = 0;
#pragma unroll
        for (int i = 0; i < 16; ++i) {
            float dx = __fsub_rn(px[i], c0);
            float dy = __fsub_rn(py[i], c1);
            float dz = __fsub_rn(pz[i], c2);
            float dd = __fadd_rn(__fadd_rn(__fmul_rn(dx, dx), __fmul_rn(dy, dy)),
                                 __fmul_rn(dz, dz));
            float nd = fminf(dist[i], dd);
            dist[i] = nd;
            int n = tid + (i << 9);
            if (i < 4) {
                if (nd > bv0) { bv0 = nd; bn0 = n; }
            } else if (i < 8) {
                if (nd > bv1) { bv1 = nd; bn1 = n; }
            } else if (i < 12) {
                if (nd > bv2) { bv2 = nd; bn2 = n; }
            } else {
                if (nd > bv3) { bv3 = nd; bn3 = n; }
            }
        }
        float bestv = bv0; int bestn = bn0;
        if (bv1 > bestv) { bestv = bv1; bestn = bn1; }
        if (bv2 > bestv) { bestv = bv2; bestn = bn2; }
        if (bv3 > bestv) { bestv = bv3; bestn = bn3; }
        u64 key = ((u64)__float_as_uint(bestv) << 32) | (unsigned)(~bestn);
        key = fps_wave_max(key);
        int pbuf = t & 1;
        if (lane == 63) wk_[pbuf][wv] = key;
        __syncthreads();
        u64 kmax = wk_[pbuf][0];
#pragma unroll
        for (int i = 1; i < 8; ++i) {
            u64 k = wk_[pbuf][i];
            if (k > kmax) kmax = k;
        }
        int kn = (int)(~(unsigned)(kmax & 0xffffffffull));
        c0 = lx[kn]; c1 = ly[kn]; c2 = lz[kn];
    }
    __syncthreads();
    float* ob = NXYZ + (size_t)b * SS * 3;
    for (int e = tid; e < SS * 3; e += 512) ob[e] = nbuf[e];
}

// K2: ball query. One wave per center. ARITHMETIC FROZEN (r18 PASS).
__global__ __launch_bounds__(256) void k_ballq(const float* __restrict__ X,
                                               const float* __restrict__ NXYZ,
                                               int* __restrict__ GI) {
    int wv = threadIdx.x >> 6, lane = threadIdx.x & 63;
    int gs = blockIdx.x * 4 + wv;           // 0..16383
    int b = gs >> 11;
    const float* xb = X + (size_t)b * NN * 3;
    float c0 = NXYZ[(size_t)gs * 3 + 0];
    float c1 = NXYZ[(size_t)gs * 3 + 1];
    float c2 = NXYZ[(size_t)gs * 3 + 2];
    float A = __fadd_rn(__fadd_rn(__fmul_rn(c0, c0), __fmul_rn(c1, c1)),
                        __fmul_rn(c2, c2));
    const float R2 = 0.04f;
    int cnt = 0, first = 0;
    int* gout = GI + ((size_t)gs << 5);
    for (int r = 0; r < 128 && cnt < 32; ++r) {
        int n = (r << 6) + lane;
        float x0 = xb[(size_t)n * 3 + 0];
        float x1 = xb[(size_t)n * 3 + 1];
        float x2 = xb[(size_t)n * 3 + 2];
        float Bx = __fadd_rn(__fadd_rn(__fmul_rn(x0, x0), __fmul_rn(x1, x1)),
                             __fmul_rn(x2, x2));
        float dot = fmaf(c2, x2, fmaf(c1, x1, __fmul_rn(c0, x0)));  // BLAS asc-FMA
        float t = __fadd_rn(__fmul_rn(-2.0f, dot), Bx);             // += B first
        float sqr = __fadd_rn(t, A);                                // += A second
        bool pred = !(sqr > R2);
        u64 mask = __ballot(pred);
        int rank = cnt + __popcll(mask & ((1ull << lane) - 1ull));
        if (pred && rank < 32) gout[rank] = n;
        if (cnt == 0 && mask) first = (r << 6) + (__ffsll((long long)mask) - 1);
        cnt += __popcll(mask);
    }
    if (cnt < 32 && lane >= cnt && lane < 32) gout[lane] = first;
}

// K3: build group features in LDS + attention block 1 + maxpool.
// r32: gather now reads transposed PT (61 consecutive floats per point).
// GEMM sections keep r30's b128 form (neutral, harmless). Everything else
// unchanged; gathered values are bit-identical copies.
__global__ __launch_bounds__(256) void k_attn1(
    const float* __restrict__ X, const float* __restrict__ NXYZ,
    const int* __restrict__ GI, const float* __restrict__ PT,
    const float* __restrict__ wq, const float* __restrict__ wk,
    const float* __restrict__ wv, const float* __restrict__ wo,
    const float* __restrict__ wp, const float* __restrict__ bp,
    float* __restrict__ FMID) {
    __shared__ float feat[32][68], qS[32][68], kS[32][68], vS[32][68];
    __shared__ float sc[32][36];
    __shared__ float pos[32][3];
    __shared__ int giS[32];
    __shared__ float ctr[3];
    int gs = blockIdx.x;
    int b = gs >> 11;
    int tid = threadIdx.x;
    if (tid < 32) giS[tid] = GI[((size_t)gs << 5) + tid];
    if (tid < 3) ctr[tid] = NXYZ[(size_t)gs * 3 + tid];
    __syncthreads();
    const float* xb = X + (size_t)b * NN * 3;
    const float* ptb = PT + (size_t)b * NN * 61;
    int d = tid & 63, g4 = tid >> 6;
    for (int jj = 0; jj < 8; ++jj) {
        int j = g4 * 8 + jj;
        int idx = giS[j];
        float val;
        if (d < 3) {
            float xv = xb[(size_t)idx * 3 + d];
            pos[j][d] = xv;
            val = __fsub_rn(xv, ctr[d]);
        } else {
            val = ptb[(size_t)idx * 61 + (d - 3)];  // consecutive per lane
        }
        feat[j][d] = val;
    }
    __syncthreads();
    float aq[8], ak[8], av[8];
#pragma unroll
    for (int i = 0; i < 8; ++i) { aq[i] = 0.f; ak[i] = 0.f; av[i] = 0.f; }
    for (int kk4 = 0; kk4 < 16; ++kk4) {
        float4 f4[8];
#pragma unroll
        for (int i = 0; i < 8; ++i)
            f4[i] = *(const float4*)&feat[g4 + 4 * i][kk4 * 4];
#pragma unroll
        for (int j = 0; j < 4; ++j) {
            int kk = kk4 * 4 + j;
            float wqv = wq[kk * 64 + d];
            float wkv = wk[kk * 64 + d];
            float wvv = wv[kk * 64 + d];
#pragma unroll
            for (int i = 0; i < 8; ++i) {
                float f = (j == 0) ? f4[i].x : (j == 1) ? f4[i].y
                                  : (j == 2) ? f4[i].z : f4[i].w;
                aq[i] = fmaf(f, wqv, aq[i]);
                ak[i] = fmaf(f, wkv, ak[i]);
                av[i] = fmaf(f, wvv, av[i]);
            }
        }
    }
    {
        float wp0 = wp[d], wp1 = wp[64 + d], wp2 = wp[128 + d];
        float bpd = bp[d];
#pragma unroll
        for (int i = 0; i < 8; ++i) {
            int j = g4 + 4 * i;
            float pterm = fmaf(pos[j][2], wp2, fmaf(pos[j][1], wp1, pos[j][0] * wp0)) + bpd;
            av[i] += pterm;
            qS[j][d] = aq[i]; kS[j][d] = ak[i]; vS[j][d] = av[i];
        }
    }
    __syncthreads();
    for (int e = tid; e < 1024; e += 256) {
        int r = e >> 5, ci = e & 31;
        float acc = 0.f;
#pragma unroll
        for (int k4 = 0; k4 < 16; ++k4) {
            float4 q4 = *(const float4*)&qS[r][k4 * 4];
            float4 kv4 = *(const float4*)&kS[ci][k4 * 4];
            acc = fmaf(q4.x, kv4.x, acc);
            acc = fmaf(q4.y, kv4.y, acc);
            acc = fmaf(q4.z, kv4.z, acc);
            acc = fmaf(q4.w, kv4.w, acc);
        }
        sc[r][ci] = acc * 0.125f;
    }
    __syncthreads();
    if (tid < 32) {
        float m = -INFINITY;
        for (int i2 = 0; i2 < 32; ++i2) m = fmaxf(m, sc[tid][i2]);
        float sum = 0.f;
        for (int i2 = 0; i2 < 32; ++i2) {
            float e2 = expf(sc[tid][i2] - m);
            sc[tid][i2] = e2; sum += e2;
        }
        float inv = 1.0f / sum;
        for (int i2 = 0; i2 < 32; ++i2) sc[tid][i2] *= inv;
    }
    __syncthreads();
    for (int e = tid; e < 2048; e += 256) {
        int j = e >> 6, dd2 = e & 63;
        float acc = 0.f;
#pragma unroll
        for (int s4 = 0; s4 < 8; ++s4) {
            float4 p4 = *(const float4*)&sc[j][s4 * 4];
            acc = fmaf(p4.x, vS[s4 * 4 + 0][dd2], acc);
            acc = fmaf(p4.y, vS[s4 * 4 + 1][dd2], acc);
            acc = fmaf(p4.z, vS[s4 * 4 + 2][dd2], acc);
            acc = fmaf(p4.w, vS[s4 * 4 + 3][dd2], acc);
        }
        qS[j][dd2] = acc;
    }
    __syncthreads();
    float o[8];
#pragma unroll
    for (int i = 0; i < 8; ++i) o[i] = feat[g4 + 4 * i][d];
    for (int kk4 = 0; kk4 < 16; ++kk4) {
        float4 a4[8];
#pragma unroll
        for (int i = 0; i < 8; ++i)
            a4[i] = *(const float4*)&qS[g4 + 4 * i][kk4 * 4];
#pragma unroll
        for (int j = 0; j < 4; ++j) {
            int kk = kk4 * 4 + j;
            float wov = wo[kk * 64 + d];
#pragma unroll
            for (int i = 0; i < 8; ++i) {
                float a = (j == 0) ? a4[i].x : (j == 1) ? a4[i].y
                                  : (j == 2) ? a4[i].z : a4[i].w;
                o[i] = fmaf(a, wov, o[i]);
            }
        }
    }
    float pm = o[0];
#pragma unroll
    for (int i = 1; i < 8; ++i) pm = fmaxf(pm, o[i]);
    __syncthreads();
    feat[g4][d] = pm;
    __syncthreads();
    if (tid < 64) {
        float mm = fmaxf(fmaxf(feat[0][tid], feat[1][tid]),
                         fmaxf(feat[2][tid], feat[3][tid]));
        FMID[((size_t)gs << 6) + tid] = mm;
    }
}

// K4: q/k/v projections for attention block 2 (rows = B*2048)
__global__ __launch_bounds__(256) void k_qkv2(
    const float* __restrict__ FMID, const float* __restrict__ NXYZ,
    const float* __restrict__ wq, const float* __restrict__ wk,
    const float* __restrict__ wv, const float* __restrict__ wp,
    const float* __restrict__ bpv,
    float* __restrict__ Q2, float* __restrict__ K2, float* __restrict__ V2) {
    __shared__ float f[4][65];
    int tid = threadIdx.x;
    int lr = tid >> 6, d = tid & 63;
    size_t row = (size_t)blockIdx.x * 4 + lr;
    f[lr][d] = FMID[row * 64 + d];
    __syncthreads();
    float aq = 0.f, ak = 0.f, av = 0.f;
    for (int kk = 0; kk < 64; ++kk) {
        float fv = f[lr][kk];
        aq = fmaf(fv, wq[kk * 64 + d], aq);
        ak = fmaf(fv, wk[kk * 64 + d], ak);
        av = fmaf(fv, wv[kk * 64 + d], av);
    }
    float p0 = NXYZ[row * 3], p1 = NXYZ[row * 3 + 1], p2 = NXYZ[row * 3 + 2];
    av += fmaf(p2, wp[128 + d], fmaf(p1, wp[64 + d], p0 * wp[d])) + bpv[d];
    Q2[row * 64 + d] = aq; K2[row * 64 + d] = ak; V2[row * 64 + d] = av;
}

// K5: attention block 2. REVERTED to the VERIFIED r29 structure (r10 = 3358
// us best): b128 QK (kT stride 68), conflict-free row-major V + shfl
// P-broadcast, 38912 B LDS => 4 blocks/CU. r31's vTT+pS rewrite regressed
// (-640 us: uncoalesced V2 staging reads + serializing pS lgkmcnt dep) —
// bpermute-PV is near-optimal here; do not rewrite again.
__global__ __launch_bounds__(256) void k_attn2(
    const float* __restrict__ Q2, const float* __restrict__ K2,
    const float* __restrict__ V2, const float* __restrict__ FMID,
    const float* __restrict__ wo, float* __restrict__ out1) {
    __shared__ float kT[64][68];  // K tile, 272B rows (16B-aligned)
    __shared__ float vT[64][68];  // V tile, row-major
    __shared__ float qSh[16][64];
    int tid = threadIdx.x;
    int wv = tid >> 6, lane = tid & 63;
    int b = blockIdx.x >> 7, rb = blockIdx.x & 127;
    size_t rbase = (size_t)b * SS + rb * 16;
    {
        int r = tid >> 4, d4 = tid & 15;  // 256 threads = 16 rows x 16 quads
        *(float4*)&qSh[r][d4 * 4] =
            *(const float4*)&Q2[(rbase + (size_t)r) * 64 + d4 * 4];
    }
    float acc[4] = {0.f, 0.f, 0.f, 0.f};
    float mr[4] = {-INFINITY, -INFINITY, -INFINITY, -INFINITY};
    float lr[4] = {0.f, 0.f, 0.f, 0.f};
    for (int tt = 0; tt < 32; ++tt) {
        __syncthreads();
        for (int e = tid; e < 1024; e += 256) {
            int r = e >> 4, d4 = e & 15;
            size_t src = ((size_t)b * SS + tt * 64 + r) * 64 + d4 * 4;
            *(float4*)&kT[r][d4 * 4] = *(const float4*)&K2[src];
            *(float4*)&vT[r][d4 * 4] = *(const float4*)&V2[src];
        }
        __syncthreads();
#pragma unroll
        for (int rr = 0; rr < 4; ++rr) {
            int lrow = wv * 4 + rr;
            float sj = 0.f;
#pragma unroll
            for (int d4 = 0; d4 < 16; ++d4) {
                float4 q4 = *(const float4*)&qSh[lrow][d4 * 4];
                float4 k4 = *(const float4*)&kT[lane][d4 * 4];
                sj = fmaf(q4.x, k4.x, sj);
                sj = fmaf(q4.y, k4.y, sj);
                sj = fmaf(q4.z, k4.z, sj);
                sj = fmaf(q4.w, k4.w, sj);
            }
            sj *= 0.125f;
            float tm = sj;
#pragma unroll
            for (int off = 32; off > 0; off >>= 1)
                tm = fmaxf(tm, __shfl_down(tm, (unsigned)off, 64));
            tm = __shfl(tm, 0, 64);
            float mnew = fmaxf(mr[rr], tm);
            float alpha = expf(mr[rr] - mnew);
            float pj = expf(sj - mnew);
            float ps = pj;
#pragma unroll
            for (int off = 32; off > 0; off >>= 1) ps += __shfl_down(ps, (unsigned)off, 64);
            ps = __shfl(ps, 0, 64);
            lr[rr] = lr[rr] * alpha + ps;
            float a2 = acc[rr] * alpha;
            for (int j = 0; j < 64; ++j) {
                float pb2 = __shfl(pj, j, 64);
                a2 = fmaf(pb2, vT[j][lane], a2);
            }
            acc[rr] = a2;
            mr[rr] = mnew;
        }
    }
#pragma unroll
    for (int rr = 0; rr < 4; ++rr) {
        int lrow = wv * 4 + rr;
        size_t row = rbase + lrow;
        float avl = acc[rr] / lr[rr];
        float o = FMID[row * 64 + lane];
        for (int kk = 0; kk < 64; ++kk) {
            float avk = __shfl(avl, kk, 64);
            o = fmaf(avk, wo[kk * 64 + lane], o);
        }
        out1[((size_t)b * 64 + lane) * SS + (size_t)(rb * 16 + lrow)] = o;
    }
}

// K6: new_xyz (B,S,3) f32 -> out0 (B,3,S) f32
__global__ void k_out0(const float* __restrict__ NXYZ, float* __restrict__ out0) {
    int e = blockIdx.x * 256 + threadIdx.x;
    if (e >= BB * 3 * SS) return;
    int s = e % SS;
    int bc = e / SS;
    int c = bc % 3;
    int b = bc / 3;
    out0[e] = NXYZ[((size_t)b * SS + s) * 3 + c];
}

extern "C" void kernel_launch(void* const* d_in, const int* in_sizes, int n_in,
                              void* d_out, int out_size, void* d_ws, size_t ws_size,
                              hipStream_t stream) {
    const float* xyz = (const float*)d_in[0];
    const float* pts = (const float*)d_in[1];
    const float* w1q = (const float*)d_in[2];
    const float* w1k = (const float*)d_in[3];
    const float* w1v = (const float*)d_in[4];
    const float* w1o = (const float*)d_in[5];
    const float* w1p = (const float*)d_in[6];
    const float* b1p = (const float*)d_in[7];
    const float* w2q = (const float*)d_in[8];
    const float* w2k = (const float*)d_in[9];
    const float* w2v = (const float*)d_in[10];
    const float* w2o = (const float*)d_in[11];
    const float* w2p = (const float*)d_in[12];
    const float* b2p = (const float*)d_in[13];

    float* X = (float*)d_ws;                               // B*N*3
    float* NXYZ = X + (size_t)BB * NN * 3;                 // B*S*3
    int* GI = (int*)(NXYZ + (size_t)BB * SS * 3);          // B*S*32
    float* FMID = (float*)(GI + (size_t)BB * SS * 32);     // B*S*64
    float* Q2 = FMID + (size_t)BB * SS * 64;
    float* K2 = Q2 + (size_t)BB * SS * 64;
    float* V2 = K2 + (size_t)BB * SS * 64;
    float* PTws = V2 + (size_t)BB * SS * 64;               // B*N*61 (16 MB)

    float* out0 = (float*)d_out;
    float* out1 = out0 + (size_t)BB * 3 * SS;

    k_transpose<<<768, 256, 0, stream>>>(xyz, X);
    k_transP<<<BB * 128, 256, 0, stream>>>(pts, PTws);
    k_fps<<<BB, 512, 0, stream>>>(X, NXYZ);
    k_ballq<<<4096, 256, 0, stream>>>(X, NXYZ, GI);
    k_attn1<<<16384, 256, 0, stream>>>(X, NXYZ, GI, PTws, w1q, w1k, w1v, w1o,
                                       w1p, b1p, FMID);
    k_qkv2<<<4096, 256, 0, stream>>>(FMID, NXYZ, w2q, w2k, w2v, w2p, b2p,
                                     Q2, K2, V2);
    k_attn2<<<1024, 256, 0, stream>>>(Q2, K2, V2, FMID, w2o, out1);
    k_out0<<<192, 256, 0, stream>>>(NXYZ, out0);
}

// Round 13
// 3238.362 us; speedup vs baseline: 1.2338x; 1.0469x over previous
//
#include <hip/hip_runtime.h>
#include <hip/hip_bf16.h>
#include <math.h>

#define BB 8
#define NN 8192
#define SS 2048
#define NSAMP 32

typedef unsigned long long u64;

// K0: transpose xyz (B,3,N) f32 -> X (B,N,3) f32
__global__ void k_transpose(const float* __restrict__ xyz, float* __restrict__ X) {
    int e = blockIdx.x * 256 + threadIdx.x;
    if (e >= BB * 3 * NN) return;
    int n = e % NN;
    int bc = e / NN;
    int c = bc % 3;
    int b = bc / 3;
    X[((size_t)(b * NN + n)) * 3 + c] = xyz[e];
}

// K0b: transpose P (B,61,N) -> PT (B,N,61). Neutral (r32) but harmless;
// kept to avoid churn. Bit-copy only.
__global__ __launch_bounds__(256) void k_transP(const float* __restrict__ P,
                                                float* __restrict__ PT) {
    __shared__ float tile[61][65];
    int blk = blockIdx.x;           // b*128 + chunk
    int b = blk >> 7, chunk = blk & 127;
    int n0 = chunk * 64;
    const float* pb = P + (size_t)b * 61 * NN;
    int tid = threadIdx.x;
    for (int e = tid; e < 61 * 64; e += 256) {
        int c = e >> 6, n = e & 63;
        tile[c][n] = pb[(size_t)c * NN + n0 + n];
    }
    __syncthreads();
    float* out = PT + ((size_t)b * NN + n0) * 61;
    for (int e = tid; e < 61 * 64; e += 256) {
        int n = e / 61, c = e % 61;
        out[e] = tile[c][n];
    }
}

// K1: farthest point sampling, one block per batch.
// ARITHMETIC FROZEN (bit-exact vs reference, r18 PASS).
// r33: 256thr x 32pts/thread + FULL r26 reduce machinery.
// Evidence chain: r21 (256thr, 32pts, pins, wpe(1,1)) hit VGPR 132 = 96
// coords + 32 dist + 4 scalars => the cache WAS resident; its regression
// was the 5-payload shfl reduce, not remat. r26's DPP u64 reduce costs ~15
// VALU instr (no DS). r25/r26 @512thr measured 2330 cyc/step vs 832 issue
// floor — the ~1500 residual is the 8-wave barrier/reduce tail. At 256thr:
// same issue cycles (thread-count-invariant), but 4-wave barrier, 4-entry
// scan, single-wave-per-SIMD DPP. Budget ~1300-1600 cyc/step.
// TELL: VGPR must be ~132-160; <=100 => allocator refused => k_fps floor.
__device__ __forceinline__ u64 fps_wave_max(u64 key) {
#define FPS_DPP_STAGE(CTRL)                                                   \
    {                                                                         \
        int lo = (int)(unsigned)(key & 0xffffffffull);                        \
        int hi = (int)(unsigned)(key >> 32);                                  \
        int lo2 = __builtin_amdgcn_update_dpp(lo, lo, CTRL, 0xF, 0xF, false); \
        int hi2 = __builtin_amdgcn_update_dpp(hi, hi, CTRL, 0xF, 0xF, false); \
        u64 k2 = ((u64)(unsigned)hi2 << 32) | (unsigned)lo2;                  \
        if (k2 > key) key = k2;                                               \
    }
    FPS_DPP_STAGE(0x121)  // row_ror:1
    FPS_DPP_STAGE(0x122)  // row_ror:2
    FPS_DPP_STAGE(0x124)  // row_ror:4
    FPS_DPP_STAGE(0x128)  // row_ror:8
    FPS_DPP_STAGE(0x142)  // row_bcast15
    FPS_DPP_STAGE(0x143)  // row_bcast31
#undef FPS_DPP_STAGE
    return key;  // lane 63 holds the full wave max
}

__global__ __launch_bounds__(256)
__attribute__((amdgpu_waves_per_eu(1, 1))) void k_fps(
    const float* __restrict__ X, float* __restrict__ NXYZ) {
    __shared__ float lx[NN], ly[NN], lz[NN];  // 96 KB winner-broadcast cache
    __shared__ float nbuf[SS * 3];            // 24 KB result buffer
    __shared__ u64 wk_[2][4];
    int b = blockIdx.x;
    int tid = threadIdx.x;
    const float* xb = X + (size_t)b * NN * 3;
    float px[32], py[32], pz[32], dist[32];
#pragma unroll
    for (int i = 0; i < 32; ++i) {
        int n = tid + (i << 8);
        px[i] = xb[(size_t)n * 3 + 0];
        py[i] = xb[(size_t)n * 3 + 1];
        pz[i] = xb[(size_t)n * 3 + 2];
        dist[i] = 1e10f;
        lx[n] = px[i]; ly[n] = py[i]; lz[n] = pz[i];
    }
    // Opaque defs: loaded values become non-rematerializable registers.
#pragma unroll
    for (int i = 0; i < 32; ++i) {
        asm volatile("" : "+v"(px[i]), "+v"(py[i]), "+v"(pz[i]));
    }
    float c0 = xb[0], c1 = xb[1], c2 = xb[2];
    int lane = tid & 63, wv = tid >> 6;  // wv in 0..3
    __syncthreads();
    for (int t = 0; t < SS; ++t) {
        if (tid == 0) {  // LDS-only; no global store in the loop
            nbuf[t * 3 + 0] = c0; nbuf[t * 3 + 1] = c1; nbuf[t * 3 + 2] = c2;
        }
        // 4 independent scan chains over ascending i-blocks; strict > keeps
        // the first (smallest-n) max within a chain; chains combined in
        // ascending-n order with strict > => identical to sequential
        // first-max over i=0..31.
        float bv0 = -1.0f, bv1 = -1.0f, bv2 = -1.0f, bv3 = -1.0f;
        int bn0 = 0, bn1 = 0, bn2 = 0, bn3 = 0;
#pragma unroll
        for (int i = 0; i < 32; ++i) {
            float dx = __fsub_rn(px[i], c0);
            float dy = __fsub_rn(py[i], c1);
            float dz = __fsub_rn(pz[i], c2);
            float dd = __fadd_rn(__fadd_rn(__fmul_rn(dx, dx), __fmul_rn(dy, dy)),
                                 __fmul_rn(dz, dz));
            float nd = fminf(dist[i], dd);
            dist[i] = nd;
            int n = tid + (i << 8);
            if (i < 8) {
                if (nd > bv0) { bv0 = nd; bn0 = n; }
            } else if (i < 16) {
                if (nd > bv1) { bv1 = nd; bn1 = n; }
            } else if (i < 24) {
                if (nd > bv2) { bv2 = nd; bn2 = n; }
            } else {
                if (nd > bv3) { bv3 = nd; bn3 = n; }
            }
        }
        float bestv = bv0; int bestn = bn0;
        if (bv1 > bestv) { bestv = bv1; bestn = bn1; }
        if (bv2 > bestv) { bestv = bv2; bestn = bn2; }
        if (bv3 > bestv) { bestv = bv3; bestn = bn3; }
        // bestv >= +0 (sums of squares, no -0/NaN) => IEEE bits are order-
        // isomorphic; u64 key max == (value, smallest-n) lexicographic max.
        u64 key = ((u64)__float_as_uint(bestv) << 32) | (unsigned)(~bestn);
        key = fps_wave_max(key);
        int pbuf = t & 1;
        if (lane == 63) wk_[pbuf][wv] = key;
        __syncthreads();
        // 4-entry cross-wave scan on packed keys (u64 max, same semantics)
        u64 kmax = wk_[pbuf][0];
#pragma unroll
        for (int i = 1; i < 4; ++i) {
            u64 k = wk_[pbuf][i];
            if (k > kmax) kmax = k;
        }
        int kn = (int)(~(unsigned)(kmax & 0xffffffffull));
        // broadcast LDS read of the winner's coords (bit-identical copy)
        c0 = lx[kn]; c1 = ly[kn]; c2 = lz[kn];
        // no trailing barrier: next step writes the other wk_ slot; the
        // write-after-next is separated from this read by the next barrier.
    }
    __syncthreads();
    // single coalesced dump of the 24 KB result buffer
    float* ob = NXYZ + (size_t)b * SS * 3;
    for (int e = tid; e < SS * 3; e += 256) ob[e] = nbuf[e];
}

// K2: ball query. One wave per center. ARITHMETIC FROZEN (r18 PASS).
__global__ __launch_bounds__(256) void k_ballq(const float* __restrict__ X,
                                               const float* __restrict__ NXYZ,
                                               int* __restrict__ GI) {
    int wv = threadIdx.x >> 6, lane = threadIdx.x & 63;
    int gs = blockIdx.x * 4 + wv;           // 0..16383
    int b = gs >> 11;
    const float* xb = X + (size_t)b * NN * 3;
    float c0 = NXYZ[(size_t)gs * 3 + 0];
    float c1 = NXYZ[(size_t)gs * 3 + 1];
    float c2 = NXYZ[(size_t)gs * 3 + 2];
    float A = __fadd_rn(__fadd_rn(__fmul_rn(c0, c0), __fmul_rn(c1, c1)),
                        __fmul_rn(c2, c2));
    const float R2 = 0.04f;
    int cnt = 0, first = 0;
    int* gout = GI + ((size_t)gs << 5);
    for (int r = 0; r < 128 && cnt < 32; ++r) {
        int n = (r << 6) + lane;
        float x0 = xb[(size_t)n * 3 + 0];
        float x1 = xb[(size_t)n * 3 + 1];
        float x2 = xb[(size_t)n * 3 + 2];
        float Bx = __fadd_rn(__fadd_rn(__fmul_rn(x0, x0), __fmul_rn(x1, x1)),
                             __fmul_rn(x2, x2));
        float dot = fmaf(c2, x2, fmaf(c1, x1, __fmul_rn(c0, x0)));  // BLAS asc-FMA
        float t = __fadd_rn(__fmul_rn(-2.0f, dot), Bx);             // += B first
        float sqr = __fadd_rn(t, A);                                // += A second
        bool pred = !(sqr > R2);
        u64 mask = __ballot(pred);
        int rank = cnt + __popcll(mask & ((1ull << lane) - 1ull));
        if (pred && rank < 32) gout[rank] = n;
        if (cnt == 0 && mask) first = (r << 6) + (__ffsll((long long)mask) - 1);
        cnt += __popcll(mask);
    }
    if (cnt < 32 && lane >= cnt && lane < 32) gout[lane] = first;
}

// K3: build group features in LDS + attention block 1 + maxpool.
// r32 state (PT gather + b128 GEMMs). UNCHANGED (control).
__global__ __launch_bounds__(256) void k_attn1(
    const float* __restrict__ X, const float* __restrict__ NXYZ,
    const int* __restrict__ GI, const float* __restrict__ PT,
    const float* __restrict__ wq, const float* __restrict__ wk,
    const float* __restrict__ wv, const float* __restrict__ wo,
    const float* __restrict__ wp, const float* __restrict__ bp,
    float* __restrict__ FMID) {
    __shared__ float feat[32][68], qS[32][68], kS[32][68], vS[32][68];
    __shared__ float sc[32][36];
    __shared__ float pos[32][3];
    __shared__ int giS[32];
    __shared__ float ctr[3];
    int gs = blockIdx.x;
    int b = gs >> 11;
    int tid = threadIdx.x;
    if (tid < 32) giS[tid] = GI[((size_t)gs << 5) + tid];
    if (tid < 3) ctr[tid] = NXYZ[(size_t)gs * 3 + tid];
    __syncthreads();
    const float* xb = X + (size_t)b * NN * 3;
    const float* ptb = PT + (size_t)b * NN * 61;
    int d = tid & 63, g4 = tid >> 6;
    for (int jj = 0; jj < 8; ++jj) {
        int j = g4 * 8 + jj;
        int idx = giS[j];
        float val;
        if (d < 3) {
            float xv = xb[(size_t)idx * 3 + d];
            pos[j][d] = xv;
            val = __fsub_rn(xv, ctr[d]);
        } else {
            val = ptb[(size_t)idx * 61 + (d - 3)];
        }
        feat[j][d] = val;
    }
    __syncthreads();
    float aq[8], ak[8], av[8];
#pragma unroll
    for (int i = 0; i < 8; ++i) { aq[i] = 0.f; ak[i] = 0.f; av[i] = 0.f; }
    for (int kk4 = 0; kk4 < 16; ++kk4) {
        float4 f4[8];
#pragma unroll
        for (int i = 0; i < 8; ++i)
            f4[i] = *(const float4*)&feat[g4 + 4 * i][kk4 * 4];
#pragma unroll
        for (int j = 0; j < 4; ++j) {
            int kk = kk4 * 4 + j;
            float wqv = wq[kk * 64 + d];
            float wkv = wk[kk * 64 + d];
            float wvv = wv[kk * 64 + d];
#pragma unroll
            for (int i = 0; i < 8; ++i) {
                float f = (j == 0) ? f4[i].x : (j == 1) ? f4[i].y
                                  : (j == 2) ? f4[i].z : f4[i].w;
                aq[i] = fmaf(f, wqv, aq[i]);
                ak[i] = fmaf(f, wkv, ak[i]);
                av[i] = fmaf(f, wvv, av[i]);
            }
        }
    }
    {
        float wp0 = wp[d], wp1 = wp[64 + d], wp2 = wp[128 + d];
        float bpd = bp[d];
#pragma unroll
        for (int i = 0; i < 8; ++i) {
            int j = g4 + 4 * i;
            float pterm = fmaf(pos[j][2], wp2, fmaf(pos[j][1], wp1, pos[j][0] * wp0)) + bpd;
            av[i] += pterm;
            qS[j][d] = aq[i]; kS[j][d] = ak[i]; vS[j][d] = av[i];
        }
    }
    __syncthreads();
    for (int e = tid; e < 1024; e += 256) {
        int r = e >> 5, ci = e & 31;
        float acc = 0.f;
#pragma unroll
        for (int k4 = 0; k4 < 16; ++k4) {
            float4 q4 = *(const float4*)&qS[r][k4 * 4];
            float4 kv4 = *(const float4*)&kS[ci][k4 * 4];
            acc = fmaf(q4.x, kv4.x, acc);
            acc = fmaf(q4.y, kv4.y, acc);
            acc = fmaf(q4.z, kv4.z, acc);
            acc = fmaf(q4.w, kv4.w, acc);
        }
        sc[r][ci] = acc * 0.125f;
    }
    __syncthreads();
    if (tid < 32) {
        float m = -INFINITY;
        for (int i2 = 0; i2 < 32; ++i2) m = fmaxf(m, sc[tid][i2]);
        float sum = 0.f;
        for (int i2 = 0; i2 < 32; ++i2) {
            float e2 = expf(sc[tid][i2] - m);
            sc[tid][i2] = e2; sum += e2;
        }
        float inv = 1.0f / sum;
        for (int i2 = 0; i2 < 32; ++i2) sc[tid][i2] *= inv;
    }
    __syncthreads();
    for (int e = tid; e < 2048; e += 256) {
        int j = e >> 6, dd2 = e & 63;
        float acc = 0.f;
#pragma unroll
        for (int s4 = 0; s4 < 8; ++s4) {
            float4 p4 = *(const float4*)&sc[j][s4 * 4];
            acc = fmaf(p4.x, vS[s4 * 4 + 0][dd2], acc);
            acc = fmaf(p4.y, vS[s4 * 4 + 1][dd2], acc);
            acc = fmaf(p4.z, vS[s4 * 4 + 2][dd2], acc);
            acc = fmaf(p4.w, vS[s4 * 4 + 3][dd2], acc);
        }
        qS[j][dd2] = acc;
    }
    __syncthreads();
    float o[8];
#pragma unroll
    for (int i = 0; i < 8; ++i) o[i] = feat[g4 + 4 * i][d];
    for (int kk4 = 0; kk4 < 16; ++kk4) {
        float4 a4[8];
#pragma unroll
        for (int i = 0; i < 8; ++i)
            a4[i] = *(const float4*)&qS[g4 + 4 * i][kk4 * 4];
#pragma unroll
        for (int j = 0; j < 4; ++j) {
            int kk = kk4 * 4 + j;
            float wov = wo[kk * 64 + d];
#pragma unroll
            for (int i = 0; i < 8; ++i) {
                float a = (j == 0) ? a4[i].x : (j == 1) ? a4[i].y
                                  : (j == 2) ? a4[i].z : a4[i].w;
                o[i] = fmaf(a, wov, o[i]);
            }
        }
    }
    float pm = o[0];
#pragma unroll
    for (int i = 1; i < 8; ++i) pm = fmaxf(pm, o[i]);
    __syncthreads();
    feat[g4][d] = pm;
    __syncthreads();
    if (tid < 64) {
        float mm = fmaxf(fmaxf(feat[0][tid], feat[1][tid]),
                         fmaxf(feat[2][tid], feat[3][tid]));
        FMID[((size_t)gs << 6) + tid] = mm;
    }
}

// K4: q/k/v projections for attention block 2 (rows = B*2048)
__global__ __launch_bounds__(256) void k_qkv2(
    const float* __restrict__ FMID, const float* __restrict__ NXYZ,
    const float* __restrict__ wq, const float* __restrict__ wk,
    const float* __restrict__ wv, const float* __restrict__ wp,
    const float* __restrict__ bpv,
    float* __restrict__ Q2, float* __restrict__ K2, float* __restrict__ V2) {
    __shared__ float f[4][65];
    int tid = threadIdx.x;
    int lr = tid >> 6, d = tid & 63;
    size_t row = (size_t)blockIdx.x * 4 + lr;
    f[lr][d] = FMID[row * 64 + d];
    __syncthreads();
    float aq = 0.f, ak = 0.f, av = 0.f;
    for (int kk = 0; kk < 64; ++kk) {
        float fv = f[lr][kk];
        aq = fmaf(fv, wq[kk * 64 + d], aq);
        ak = fmaf(fv, wk[kk * 64 + d], ak);
        av = fmaf(fv, wv[kk * 64 + d], av);
    }
    float p0 = NXYZ[row * 3], p1 = NXYZ[row * 3 + 1], p2 = NXYZ[row * 3 + 2];
    av += fmaf(p2, wp[128 + d], fmaf(p1, wp[64 + d], p0 * wp[d])) + bpv[d];
    Q2[row * 64 + d] = aq; K2[row * 64 + d] = ak; V2[row * 64 + d] = av;
}

// K5: attention block 2. VERIFIED r29 structure (r10 best). UNCHANGED.
__global__ __launch_bounds__(256) void k_attn2(
    const float* __restrict__ Q2, const float* __restrict__ K2,
    const float* __restrict__ V2, const float* __restrict__ FMID,
    const float* __restrict__ wo, float* __restrict__ out1) {
    __shared__ float kT[64][68];  // K tile, 272B rows (16B-aligned)
    __shared__ float vT[64][68];  // V tile, row-major
    __shared__ float qSh[16][64];
    int tid = threadIdx.x;
    int wv = tid >> 6, lane = tid & 63;
    int b = blockIdx.x >> 7, rb = blockIdx.x & 127;
    size_t rbase = (size_t)b * SS + rb * 16;
    {
        int r = tid >> 4, d4 = tid & 15;  // 256 threads = 16 rows x 16 quads
        *(float4*)&qSh[r][d4 * 4] =
            *(const float4*)&Q2[(rbase + (size_t)r) * 64 + d4 * 4];
    }
    float acc[4] = {0.f, 0.f, 0.f, 0.f};
    float mr[4] = {-INFINITY, -INFINITY, -INFINITY, -INFINITY};
    float lr[4] = {0.f, 0.f, 0.f, 0.f};
    for (int tt = 0; tt < 32; ++tt) {
        __syncthreads();
        for (int e = tid; e < 1024; e += 256) {
            int r = e >> 4, d4 = e & 15;
            size_t src = ((size_t)b * SS + tt * 64 + r) * 64 + d4 * 4;
            *(float4*)&kT[r][d4 * 4] = *(const float4*)&K2[src];
            *(float4*)&vT[r][d4 * 4] = *(const float4*)&V2[src];
        }
        __syncthreads();
#pragma unroll
        for (int rr = 0; rr < 4; ++rr) {
            int lrow = wv * 4 + rr;
            float sj = 0.f;
#pragma unroll
            for (int d4 = 0; d4 < 16; ++d4) {
                float4 q4 = *(const float4*)&qSh[lrow][d4 * 4];
                float4 k4 = *(const float4*)&kT[lane][d4 * 4];
                sj = fmaf(q4.x, k4.x, sj);
                sj = fmaf(q4.y, k4.y, sj);
                sj = fmaf(q4.z, k4.z, sj);
                sj = fmaf(q4.w, k4.w, sj);
            }
            sj *= 0.125f;
            float tm = sj;
#pragma unroll
            for (int off = 32; off > 0; off >>= 1)
                tm = fmaxf(tm, __shfl_down(tm, (unsigned)off, 64));
            tm = __shfl(tm, 0, 64);
            float mnew = fmaxf(mr[rr], tm);
            float alpha = expf(mr[rr] - mnew);
            float pj = expf(sj - mnew);
            float ps = pj;
#pragma unroll
            for (int off = 32; off > 0; off >>= 1) ps += __shfl_down(ps, (unsigned)off, 64);
            ps = __shfl(ps, 0, 64);
            lr[rr] = lr[rr] * alpha + ps;
            float a2 = acc[rr] * alpha;
            for (int j = 0; j < 64; ++j) {
                float pb2 = __shfl(pj, j, 64);
                a2 = fmaf(pb2, vT[j][lane], a2);
            }
            acc[rr] = a2;
            mr[rr] = mnew;
        }
    }
#pragma unroll
    for (int rr = 0; rr < 4; ++rr) {
        int lrow = wv * 4 + rr;
        size_t row = rbase + lrow;
        float avl = acc[rr] / lr[rr];
        float o = FMID[row * 64 + lane];
        for (int kk = 0; kk < 64; ++kk) {
            float avk = __shfl(avl, kk, 64);
            o = fmaf(avk, wo[kk * 64 + lane], o);
        }
        out1[((size_t)b * 64 + lane) * SS + (size_t)(rb * 16 + lrow)] = o;
    }
}

// K6: new_xyz (B,S,3) f32 -> out0 (B,3,S) f32
__global__ void k_out0(const float* __restrict__ NXYZ, float* __restrict__ out0) {
    int e = blockIdx.x * 256 + threadIdx.x;
    if (e >= BB * 3 * SS) return;
    int s = e % SS;
    int bc = e / SS;
    int c = bc % 3;
    int b = bc / 3;
    out0[e] = NXYZ[((size_t)b * SS + s) * 3 + c];
}

extern "C" void kernel_launch(void* const* d_in, const int* in_sizes, int n_in,
                              void* d_out, int out_size, void* d_ws, size_t ws_size,
                              hipStream_t stream) {
    const float* xyz = (const float*)d_in[0];
    const float* pts = (const float*)d_in[1];
    const float* w1q = (const float*)d_in[2];
    const float* w1k = (const float*)d_in[3];
    const float* w1v = (const float*)d_in[4];
    const float* w1o = (const float*)d_in[5];
    const float* w1p = (const float*)d_in[6];
    const float* b1p = (const float*)d_in[7];
    const float* w2q = (const float*)d_in[8];
    const float* w2k = (const float*)d_in[9];
    const float* w2v = (const float*)d_in[10];
    const float* w2o = (const float*)d_in[11];
    const float* w2p = (const float*)d_in[12];
    const float* b2p = (const float*)d_in[13];

    float* X = (float*)d_ws;                               // B*N*3
    float* NXYZ = X + (size_t)BB * NN * 3;                 // B*S*3
    int* GI = (int*)(NXYZ + (size_t)BB * SS * 3);          // B*S*32
    float* FMID = (float*)(GI + (size_t)BB * SS * 32);     // B*S*64
    float* Q2 = FMID + (size_t)BB * SS * 64;
    float* K2 = Q2 + (size_t)BB * SS * 64;
    float* V2 = K2 + (size_t)BB * SS * 64;
    float* PTws = V2 + (size_t)BB * SS * 64;               // B*N*61 (16 MB)

    float* out0 = (float*)d_out;
    float* out1 = out0 + (size_t)BB * 3 * SS;

    k_transpose<<<768, 256, 0, stream>>>(xyz, X);
    k_transP<<<BB * 128, 256, 0, stream>>>(pts, PTws);
    k_fps<<<BB, 256, 0, stream>>>(X, NXYZ);
    k_ballq<<<4096, 256, 0, stream>>>(X, NXYZ, GI);
    k_attn1<<<16384, 256, 0, stream>>>(X, NXYZ, GI, PTws, w1q, w1k, w1v, w1o,
                                       w1p, b1p, FMID);
    k_qkv2<<<4096, 256, 0, stream>>>(FMID, NXYZ, w2q, w2k, w2v, w2p, b2p,
                                     Q2, K2, V2);
    k_attn2<<<1024, 256, 0, stream>>>(Q2, K2, V2, FMID, w2o, out1);
    k_out0<<<192, 256, 0, stream>>>(NXYZ, out0);
}

// Round 14
// 3176.568 us; speedup vs baseline: 1.2578x; 1.0195x over previous
//
#include <hip/hip_runtime.h>
#include <hip/hip_bf16.h>
#include <math.h>

#define BB 8
#define NN 8192
#define SS 2048
#define NSAMP 32

typedef unsigned long long u64;

// K0: transpose xyz (B,3,N) f32 -> X (B,N,3) f32
__global__ void k_transpose(const float* __restrict__ xyz, float* __restrict__ X) {
    int e = blockIdx.x * 256 + threadIdx.x;
    if (e >= BB * 3 * NN) return;
    int n = e % NN;
    int bc = e / NN;
    int c = bc % 3;
    int b = bc / 3;
    X[((size_t)(b * NN + n)) * 3 + c] = xyz[e];
}

// K0b: transpose P (B,61,N) -> PT (B,N,61). Bit-copy only.
__global__ __launch_bounds__(256) void k_transP(const float* __restrict__ P,
                                                float* __restrict__ PT) {
    __shared__ float tile[61][65];
    int blk = blockIdx.x;           // b*128 + chunk
    int b = blk >> 7, chunk = blk & 127;
    int n0 = chunk * 64;
    const float* pb = P + (size_t)b * 61 * NN;
    int tid = threadIdx.x;
    for (int e = tid; e < 61 * 64; e += 256) {
        int c = e >> 6, n = e & 63;
        tile[c][n] = pb[(size_t)c * NN + n0 + n];
    }
    __syncthreads();
    float* out = PT + ((size_t)b * NN + n0) * 61;
    for (int e = tid; e < 61 * 64; e += 256) {
        int n = e / 61, c = e % 61;
        out[e] = tile[c][n];
    }
}

// K1: farthest point sampling. ARITHMETIC FROZEN (r18 PASS).
// r33 VERIFIED (1863 us, VGPR 132 = coords resident): 256thr x 32pts in
// registers, DPP u64-key reduce, nbuf output buffer, LDS coord mirror for
// winner broadcast. Step ~2180 cyc = 832 issue floor + ~1350 serial tail
// (DPP + barrier + scan + broadcast latencies at 1 wave/SIMD) — structural
// floor for this algorithm shape. UNCHANGED (control).
__device__ __forceinline__ u64 fps_wave_max(u64 key) {
#define FPS_DPP_STAGE(CTRL)                                                   \
    {                                                                         \
        int lo = (int)(unsigned)(key & 0xffffffffull);                        \
        int hi = (int)(unsigned)(key >> 32);                                  \
        int lo2 = __builtin_amdgcn_update_dpp(lo, lo, CTRL, 0xF, 0xF, false); \
        int hi2 = __builtin_amdgcn_update_dpp(hi, hi, CTRL, 0xF, 0xF, false); \
        u64 k2 = ((u64)(unsigned)hi2 << 32) | (unsigned)lo2;                  \
        if (k2 > key) key = k2;                                               \
    }
    FPS_DPP_STAGE(0x121)  // row_ror:1
    FPS_DPP_STAGE(0x122)  // row_ror:2
    FPS_DPP_STAGE(0x124)  // row_ror:4
    FPS_DPP_STAGE(0x128)  // row_ror:8
    FPS_DPP_STAGE(0x142)  // row_bcast15
    FPS_DPP_STAGE(0x143)  // row_bcast31
#undef FPS_DPP_STAGE
    return key;  // lane 63 holds the full wave max
}

__global__ __launch_bounds__(256)
__attribute__((amdgpu_waves_per_eu(1, 1))) void k_fps(
    const float* __restrict__ X, float* __restrict__ NXYZ) {
    __shared__ float lx[NN], ly[NN], lz[NN];  // 96 KB winner-broadcast cache
    __shared__ float nbuf[SS * 3];            // 24 KB result buffer
    __shared__ u64 wk_[2][4];
    int b = blockIdx.x;
    int tid = threadIdx.x;
    const float* xb = X + (size_t)b * NN * 3;
    float px[32], py[32], pz[32], dist[32];
#pragma unroll
    for (int i = 0; i < 32; ++i) {
        int n = tid + (i << 8);
        px[i] = xb[(size_t)n * 3 + 0];
        py[i] = xb[(size_t)n * 3 + 1];
        pz[i] = xb[(size_t)n * 3 + 2];
        dist[i] = 1e10f;
        lx[n] = px[i]; ly[n] = py[i]; lz[n] = pz[i];
    }
#pragma unroll
    for (int i = 0; i < 32; ++i) {
        asm volatile("" : "+v"(px[i]), "+v"(py[i]), "+v"(pz[i]));
    }
    float c0 = xb[0], c1 = xb[1], c2 = xb[2];
    int lane = tid & 63, wv = tid >> 6;  // wv in 0..3
    __syncthreads();
    for (int t = 0; t < SS; ++t) {
        if (tid == 0) {
            nbuf[t * 3 + 0] = c0; nbuf[t * 3 + 1] = c1; nbuf[t * 3 + 2] = c2;
        }
        float bv0 = -1.0f, bv1 = -1.0f, bv2 = -1.0f, bv3 = -1.0f;
        int bn0 = 0, bn1 = 0, bn2 = 0, bn3 = 0;
#pragma unroll
        for (int i = 0; i < 32; ++i) {
            float dx = __fsub_rn(px[i], c0);
            float dy = __fsub_rn(py[i], c1);
            float dz = __fsub_rn(pz[i], c2);
            float dd = __fadd_rn(__fadd_rn(__fmul_rn(dx, dx), __fmul_rn(dy, dy)),
                                 __fmul_rn(dz, dz));
            float nd = fminf(dist[i], dd);
            dist[i] = nd;
            int n = tid + (i << 8);
            if (i < 8) {
                if (nd > bv0) { bv0 = nd; bn0 = n; }
            } else if (i < 16) {
                if (nd > bv1) { bv1 = nd; bn1 = n; }
            } else if (i < 24) {
                if (nd > bv2) { bv2 = nd; bn2 = n; }
            } else {
                if (nd > bv3) { bv3 = nd; bn3 = n; }
            }
        }
        float bestv = bv0; int bestn = bn0;
        if (bv1 > bestv) { bestv = bv1; bestn = bn1; }
        if (bv2 > bestv) { bestv = bv2; bestn = bn2; }
        if (bv3 > bestv) { bestv = bv3; bestn = bn3; }
        u64 key = ((u64)__float_as_uint(bestv) << 32) | (unsigned)(~bestn);
        key = fps_wave_max(key);
        int pbuf = t & 1;
        if (lane == 63) wk_[pbuf][wv] = key;
        __syncthreads();
        u64 kmax = wk_[pbuf][0];
#pragma unroll
        for (int i = 1; i < 4; ++i) {
            u64 k = wk_[pbuf][i];
            if (k > kmax) kmax = k;
        }
        int kn = (int)(~(unsigned)(kmax & 0xffffffffull));
        c0 = lx[kn]; c1 = ly[kn]; c2 = lz[kn];
    }
    __syncthreads();
    float* ob = NXYZ + (size_t)b * SS * 3;
    for (int e = tid; e < SS * 3; e += 256) ob[e] = nbuf[e];
}

// K2: ball query. One wave per center. ARITHMETIC FROZEN (r18 PASS).
__global__ __launch_bounds__(256) void k_ballq(const float* __restrict__ X,
                                               const float* __restrict__ NXYZ,
                                               int* __restrict__ GI) {
    int wv = threadIdx.x >> 6, lane = threadIdx.x & 63;
    int gs = blockIdx.x * 4 + wv;           // 0..16383
    int b = gs >> 11;
    const float* xb = X + (size_t)b * NN * 3;
    float c0 = NXYZ[(size_t)gs * 3 + 0];
    float c1 = NXYZ[(size_t)gs * 3 + 1];
    float c2 = NXYZ[(size_t)gs * 3 + 2];
    float A = __fadd_rn(__fadd_rn(__fmul_rn(c0, c0), __fmul_rn(c1, c1)),
                        __fmul_rn(c2, c2));
    const float R2 = 0.04f;
    int cnt = 0, first = 0;
    int* gout = GI + ((size_t)gs << 5);
    for (int r = 0; r < 128 && cnt < 32; ++r) {
        int n = (r << 6) + lane;
        float x0 = xb[(size_t)n * 3 + 0];
        float x1 = xb[(size_t)n * 3 + 1];
        float x2 = xb[(size_t)n * 3 + 2];
        float Bx = __fadd_rn(__fadd_rn(__fmul_rn(x0, x0), __fmul_rn(x1, x1)),
                             __fmul_rn(x2, x2));
        float dot = fmaf(c2, x2, fmaf(c1, x1, __fmul_rn(c0, x0)));  // BLAS asc-FMA
        float t = __fadd_rn(__fmul_rn(-2.0f, dot), Bx);             // += B first
        float sqr = __fadd_rn(t, A);                                // += A second
        bool pred = !(sqr > R2);
        u64 mask = __ballot(pred);
        int rank = cnt + __popcll(mask & ((1ull << lane) - 1ull));
        if (pred && rank < 32) gout[rank] = n;
        if (cnt == 0 && mask) first = (r << 6) + (__ffsll((long long)mask) - 1);
        cnt += __popcll(mask);
    }
    if (cnt < 32 && lane >= cnt && lane < 32) gout[lane] = first;
}

// K3: attention block 1 + maxpool.
// r34: OPERAND SHARING (bit-exact — every output's fma chain keeps the
// exact ascending k4/s4 order with x,y,z,w sub-order):
//  - score GEMM: each thread's 4 output rows (r = r0+8k) share kS[ci] —
//    kv4 hoisted: 64 -> 16 b128 reads/thread.
//  - AV: each thread's 8 output rows (j = j0+4k) share the vS[*][dd2]
//    column — v scalars hoisted: 256 -> 32 scalar reads/thread.
// Gather via PT; QKV/outproj keep r30 b128 form.
__global__ __launch_bounds__(256) void k_attn1(
    const float* __restrict__ X, const float* __restrict__ NXYZ,
    const int* __restrict__ GI, const float* __restrict__ PT,
    const float* __restrict__ wq, const float* __restrict__ wk,
    const float* __restrict__ wv, const float* __restrict__ wo,
    const float* __restrict__ wp, const float* __restrict__ bp,
    float* __restrict__ FMID) {
    __shared__ float feat[32][68], qS[32][68], kS[32][68], vS[32][68];
    __shared__ float sc[32][36];
    __shared__ float pos[32][3];
    __shared__ int giS[32];
    __shared__ float ctr[3];
    int gs = blockIdx.x;
    int b = gs >> 11;
    int tid = threadIdx.x;
    if (tid < 32) giS[tid] = GI[((size_t)gs << 5) + tid];
    if (tid < 3) ctr[tid] = NXYZ[(size_t)gs * 3 + tid];
    __syncthreads();
    const float* xb = X + (size_t)b * NN * 3;
    const float* ptb = PT + (size_t)b * NN * 61;
    int d = tid & 63, g4 = tid >> 6;
    for (int jj = 0; jj < 8; ++jj) {
        int j = g4 * 8 + jj;
        int idx = giS[j];
        float val;
        if (d < 3) {
            float xv = xb[(size_t)idx * 3 + d];
            pos[j][d] = xv;
            val = __fsub_rn(xv, ctr[d]);
        } else {
            val = ptb[(size_t)idx * 61 + (d - 3)];
        }
        feat[j][d] = val;
    }
    __syncthreads();
    float aq[8], ak[8], av[8];
#pragma unroll
    for (int i = 0; i < 8; ++i) { aq[i] = 0.f; ak[i] = 0.f; av[i] = 0.f; }
    for (int kk4 = 0; kk4 < 16; ++kk4) {
        float4 f4[8];
#pragma unroll
        for (int i = 0; i < 8; ++i)
            f4[i] = *(const float4*)&feat[g4 + 4 * i][kk4 * 4];
#pragma unroll
        for (int j = 0; j < 4; ++j) {
            int kk = kk4 * 4 + j;
            float wqv = wq[kk * 64 + d];
            float wkv = wk[kk * 64 + d];
            float wvv = wv[kk * 64 + d];
#pragma unroll
            for (int i = 0; i < 8; ++i) {
                float f = (j == 0) ? f4[i].x : (j == 1) ? f4[i].y
                                  : (j == 2) ? f4[i].z : f4[i].w;
                aq[i] = fmaf(f, wqv, aq[i]);
                ak[i] = fmaf(f, wkv, ak[i]);
                av[i] = fmaf(f, wvv, av[i]);
            }
        }
    }
    {
        float wp0 = wp[d], wp1 = wp[64 + d], wp2 = wp[128 + d];
        float bpd = bp[d];
#pragma unroll
        for (int i = 0; i < 8; ++i) {
            int j = g4 + 4 * i;
            float pterm = fmaf(pos[j][2], wp2, fmaf(pos[j][1], wp1, pos[j][0] * wp0)) + bpd;
            av[i] += pterm;
            qS[j][d] = aq[i]; kS[j][d] = ak[i]; vS[j][d] = av[i];
        }
    }
    __syncthreads();
    // score GEMM with shared kS column: thread (r0,ci) does rows r0+8k.
    {
        int ci = tid & 31, r0 = tid >> 5;  // r0 in 0..7
        float accv[4] = {0.f, 0.f, 0.f, 0.f};
#pragma unroll
        for (int k4 = 0; k4 < 16; ++k4) {
            float4 kv4 = *(const float4*)&kS[ci][k4 * 4];
#pragma unroll
            for (int rr = 0; rr < 4; ++rr) {
                float4 q4 = *(const float4*)&qS[r0 + 8 * rr][k4 * 4];
                accv[rr] = fmaf(q4.x, kv4.x, accv[rr]);
                accv[rr] = fmaf(q4.y, kv4.y, accv[rr]);
                accv[rr] = fmaf(q4.z, kv4.z, accv[rr]);
                accv[rr] = fmaf(q4.w, kv4.w, accv[rr]);
            }
        }
#pragma unroll
        for (int rr = 0; rr < 4; ++rr) sc[r0 + 8 * rr][ci] = accv[rr] * 0.125f;
    }
    __syncthreads();
    if (tid < 32) {
        float m = -INFINITY;
        for (int i2 = 0; i2 < 32; ++i2) m = fmaxf(m, sc[tid][i2]);
        float sum = 0.f;
        for (int i2 = 0; i2 < 32; ++i2) {
            float e2 = expf(sc[tid][i2] - m);
            sc[tid][i2] = e2; sum += e2;
        }
        float inv = 1.0f / sum;
        for (int i2 = 0; i2 < 32; ++i2) sc[tid][i2] *= inv;
    }
    __syncthreads();
    // AV with shared vS column: thread (j0,dd2) does rows j0+4k.
    {
        int dd2 = tid & 63, j0 = tid >> 6;  // j0 in 0..3
        float accv[8];
#pragma unroll
        for (int jj = 0; jj < 8; ++jj) accv[jj] = 0.f;
#pragma unroll
        for (int s4 = 0; s4 < 8; ++s4) {
            float v0 = vS[s4 * 4 + 0][dd2];
            float v1 = vS[s4 * 4 + 1][dd2];
            float v2 = vS[s4 * 4 + 2][dd2];
            float v3 = vS[s4 * 4 + 3][dd2];
#pragma unroll
            for (int jj = 0; jj < 8; ++jj) {
                float4 p4 = *(const float4*)&sc[j0 + 4 * jj][s4 * 4];
                accv[jj] = fmaf(p4.x, v0, accv[jj]);
                accv[jj] = fmaf(p4.y, v1, accv[jj]);
                accv[jj] = fmaf(p4.z, v2, accv[jj]);
                accv[jj] = fmaf(p4.w, v3, accv[jj]);
            }
        }
        __syncthreads();  // all sc/vS reads done before qS overwrite below
#pragma unroll
        for (int jj = 0; jj < 8; ++jj) qS[j0 + 4 * jj][dd2] = accv[jj];
    }
    __syncthreads();
    float o[8];
#pragma unroll
    for (int i = 0; i < 8; ++i) o[i] = feat[g4 + 4 * i][d];
    for (int kk4 = 0; kk4 < 16; ++kk4) {
        float4 a4[8];
#pragma unroll
        for (int i = 0; i < 8; ++i)
            a4[i] = *(const float4*)&qS[g4 + 4 * i][kk4 * 4];
#pragma unroll
        for (int j = 0; j < 4; ++j) {
            int kk = kk4 * 4 + j;
            float wov = wo[kk * 64 + d];
#pragma unroll
            for (int i = 0; i < 8; ++i) {
                float a = (j == 0) ? a4[i].x : (j == 1) ? a4[i].y
                                  : (j == 2) ? a4[i].z : a4[i].w;
                o[i] = fmaf(a, wov, o[i]);
            }
        }
    }
    float pm = o[0];
#pragma unroll
    for (int i = 1; i < 8; ++i) pm = fmaxf(pm, o[i]);
    __syncthreads();
    feat[g4][d] = pm;
    __syncthreads();
    if (tid < 64) {
        float mm = fmaxf(fmaxf(feat[0][tid], feat[1][tid]),
                         fmaxf(feat[2][tid], feat[3][tid]));
        FMID[((size_t)gs << 6) + tid] = mm;
    }
}

// K4: q/k/v projections for attention block 2 (rows = B*2048)
__global__ __launch_bounds__(256) void k_qkv2(
    const float* __restrict__ FMID, const float* __restrict__ NXYZ,
    const float* __restrict__ wq, const float* __restrict__ wk,
    const float* __restrict__ wv, const float* __restrict__ wp,
    const float* __restrict__ bpv,
    float* __restrict__ Q2, float* __restrict__ K2, float* __restrict__ V2) {
    __shared__ float f[4][65];
    int tid = threadIdx.x;
    int lr = tid >> 6, d = tid & 63;
    size_t row = (size_t)blockIdx.x * 4 + lr;
    f[lr][d] = FMID[row * 64 + d];
    __syncthreads();
    float aq = 0.f, ak = 0.f, av = 0.f;
    for (int kk = 0; kk < 64; ++kk) {
        float fv = f[lr][kk];
        aq = fmaf(fv, wq[kk * 64 + d], aq);
        ak = fmaf(fv, wk[kk * 64 + d], ak);
        av = fmaf(fv, wv[kk * 64 + d], av);
    }
    float p0 = NXYZ[row * 3], p1 = NXYZ[row * 3 + 1], p2 = NXYZ[row * 3 + 2];
    av += fmaf(p2, wp[128 + d], fmaf(p1, wp[64 + d], p0 * wp[d])) + bpv[d];
    Q2[row * 64 + d] = aq; K2[row * 64 + d] = ak; V2[row * 64 + d] = av;
}

// K5: attention block 2 (r29 base structure).
// r34: OPERAND SHARING across the 4 rr (bit-exact — each rr's chain keeps
// ascending d4/j order with x,y,z,w sub-order):
//  - QK: kT[lane][d4] identical for all rr -> hoisted, 64 -> 16 b128/tile.
//  - PV: vT[j][lane] identical for all rr -> hoisted, 256 -> 64 scalar;
//    the 4 shfls per j are independent -> better DS pipelining.
// VGPR budget watched: +~12 (sj/pj/alpha arrays) on 100 must stay <= 128
// to keep 4 blocks/CU (r28 lesson).
__global__ __launch_bounds__(256) void k_attn2(
    const float* __restrict__ Q2, const float* __restrict__ K2,
    const float* __restrict__ V2, const float* __restrict__ FMID,
    const float* __restrict__ wo, float* __restrict__ out1) {
    __shared__ float kT[64][68];  // K tile, 272B rows (16B-aligned)
    __shared__ float vT[64][68];  // V tile, row-major
    __shared__ float qSh[16][64];
    int tid = threadIdx.x;
    int wv = tid >> 6, lane = tid & 63;
    int b = blockIdx.x >> 7, rb = blockIdx.x & 127;
    size_t rbase = (size_t)b * SS + rb * 16;
    {
        int r = tid >> 4, d4 = tid & 15;
        *(float4*)&qSh[r][d4 * 4] =
            *(const float4*)&Q2[(rbase + (size_t)r) * 64 + d4 * 4];
    }
    float acc[4] = {0.f, 0.f, 0.f, 0.f};
    float mr[4] = {-INFINITY, -INFINITY, -INFINITY, -INFINITY};
    float lr[4] = {0.f, 0.f, 0.f, 0.f};
    for (int tt = 0; tt < 32; ++tt) {
        __syncthreads();
        for (int e = tid; e < 1024; e += 256) {
            int r = e >> 4, d4 = e & 15;
            size_t src = ((size_t)b * SS + tt * 64 + r) * 64 + d4 * 4;
            *(float4*)&kT[r][d4 * 4] = *(const float4*)&K2[src];
            *(float4*)&vT[r][d4 * 4] = *(const float4*)&V2[src];
        }
        __syncthreads();
        // QK for all 4 rr jointly; kT read once per d4 (shared operand).
        float sj[4] = {0.f, 0.f, 0.f, 0.f};
#pragma unroll
        for (int d4 = 0; d4 < 16; ++d4) {
            float4 k4 = *(const float4*)&kT[lane][d4 * 4];
#pragma unroll
            for (int rr = 0; rr < 4; ++rr) {
                float4 q4 = *(const float4*)&qSh[wv * 4 + rr][d4 * 4];
                sj[rr] = fmaf(q4.x, k4.x, sj[rr]);
                sj[rr] = fmaf(q4.y, k4.y, sj[rr]);
                sj[rr] = fmaf(q4.z, k4.z, sj[rr]);
                sj[rr] = fmaf(q4.w, k4.w, sj[rr]);
            }
        }
        // online-softmax bookkeeping per rr (unchanged semantics/order)
        float pj[4], alpha[4];
#pragma unroll
        for (int rr = 0; rr < 4; ++rr) {
            float s = sj[rr] * 0.125f;
            float tm = s;
#pragma unroll
            for (int off = 32; off > 0; off >>= 1)
                tm = fmaxf(tm, __shfl_down(tm, (unsigned)off, 64));
            tm = __shfl(tm, 0, 64);
            float mnew = fmaxf(mr[rr], tm);
            alpha[rr] = expf(mr[rr] - mnew);
            pj[rr] = expf(s - mnew);
            float ps = pj[rr];
#pragma unroll
            for (int off = 32; off > 0; off >>= 1) ps += __shfl_down(ps, (unsigned)off, 64);
            ps = __shfl(ps, 0, 64);
            lr[rr] = lr[rr] * alpha[rr] + ps;
            mr[rr] = mnew;
        }
        // PV for all 4 rr jointly; vT read once per j (shared operand).
        float a2[4];
#pragma unroll
        for (int rr = 0; rr < 4; ++rr) a2[rr] = acc[rr] * alpha[rr];
        for (int j = 0; j < 64; ++j) {
            float v = vT[j][lane];
#pragma unroll
            for (int rr = 0; rr < 4; ++rr) {
                float pb2 = __shfl(pj[rr], j, 64);
                a2[rr] = fmaf(pb2, v, a2[rr]);
            }
        }
#pragma unroll
        for (int rr = 0; rr < 4; ++rr) acc[rr] = a2[rr];
    }
#pragma unroll
    for (int rr = 0; rr < 4; ++rr) {
        int lrow = wv * 4 + rr;
        size_t row = rbase + lrow;
        float avl = acc[rr] / lr[rr];
        float o = FMID[row * 64 + lane];
        for (int kk = 0; kk < 64; ++kk) {
            float avk = __shfl(avl, kk, 64);
            o = fmaf(avk, wo[kk * 64 + lane], o);
        }
        out1[((size_t)b * 64 + lane) * SS + (size_t)(rb * 16 + lrow)] = o;
    }
}

// K6: new_xyz (B,S,3) f32 -> out0 (B,3,S) f32
__global__ void k_out0(const float* __restrict__ NXYZ, float* __restrict__ out0) {
    int e = blockIdx.x * 256 + threadIdx.x;
    if (e >= BB * 3 * SS) return;
    int s = e % SS;
    int bc = e / SS;
    int c = bc % 3;
    int b = bc / 3;
    out0[e] = NXYZ[((size_t)b * SS + s) * 3 + c];
}

extern "C" void kernel_launch(void* const* d_in, const int* in_sizes, int n_in,
                              void* d_out, int out_size, void* d_ws, size_t ws_size,
                              hipStream_t stream) {
    const float* xyz = (const float*)d_in[0];
    const float* pts = (const float*)d_in[1];
    const float* w1q = (const float*)d_in[2];
    const float* w1k = (const float*)d_in[3];
    const float* w1v = (const float*)d_in[4];
    const float* w1o = (const float*)d_in[5];
    const float* w1p = (const float*)d_in[6];
    const float* b1p = (const float*)d_in[7];
    const float* w2q = (const float*)d_in[8];
    const float* w2k = (const float*)d_in[9];
    const float* w2v = (const float*)d_in[10];
    const float* w2o = (const float*)d_in[11];
    const float* w2p = (const float*)d_in[12];
    const float* b2p = (const float*)d_in[13];

    float* X = (float*)d_ws;                               // B*N*3
    float* NXYZ = X + (size_t)BB * NN * 3;                 // B*S*3
    int* GI = (int*)(NXYZ + (size_t)BB * SS * 3);          // B*S*32
    float* FMID = (float*)(GI + (size_t)BB * SS * 32);     // B*S*64
    float* Q2 = FMID + (size_t)BB * SS * 64;
    float* K2 = Q2 + (size_t)BB * SS * 64;
    float* V2 = K2 + (size_t)BB * SS * 64;
    float* PTws = V2 + (size_t)BB * SS * 64;               // B*N*61 (16 MB)

    float* out0 = (float*)d_out;
    float* out1 = out0 + (size_t)BB * 3 * SS;

    k_transpose<<<768, 256, 0, stream>>>(xyz, X);
    k_transP<<<BB * 128, 256, 0, stream>>>(pts, PTws);
    k_fps<<<BB, 256, 0, stream>>>(X, NXYZ);
    k_ballq<<<4096, 256, 0, stream>>>(X, NXYZ, GI);
    k_attn1<<<16384, 256, 0, stream>>>(X, NXYZ, GI, PTws, w1q, w1k, w1v, w1o,
                                       w1p, b1p, FMID);
    k_qkv2<<<4096, 256, 0, stream>>>(FMID, NXYZ, w2q, w2k, w2v, w2p, b2p,
                                     Q2, K2, V2);
    k_attn2<<<1024, 256, 0, stream>>>(Q2, K2, V2, FMID, w2o, out1);
    k_out0<<<192, 256, 0, stream>>>(NXYZ, out0);
}

// Round 15
// 3138.234 us; speedup vs baseline: 1.2731x; 1.0122x over previous
//
#include <hip/hip_runtime.h>
#include <hip/hip_bf16.h>
#include <math.h>

#define BB 8
#define NN 8192
#define SS 2048
#define NSAMP 32

typedef unsigned long long u64;

// K0: transpose xyz (B,3,N) f32 -> X (B,N,3) f32
__global__ void k_transpose(const float* __restrict__ xyz, float* __restrict__ X) {
    int e = blockIdx.x * 256 + threadIdx.x;
    if (e >= BB * 3 * NN) return;
    int n = e % NN;
    int bc = e / NN;
    int c = bc % 3;
    int b = bc / 3;
    X[((size_t)(b * NN + n)) * 3 + c] = xyz[e];
}

// K0b: transpose P (B,61,N) -> PT (B,N,61). Bit-copy only.
__global__ __launch_bounds__(256) void k_transP(const float* __restrict__ P,
                                                float* __restrict__ PT) {
    __shared__ float tile[61][65];
    int blk = blockIdx.x;           // b*128 + chunk
    int b = blk >> 7, chunk = blk & 127;
    int n0 = chunk * 64;
    const float* pb = P + (size_t)b * 61 * NN;
    int tid = threadIdx.x;
    for (int e = tid; e < 61 * 64; e += 256) {
        int c = e >> 6, n = e & 63;
        tile[c][n] = pb[(size_t)c * NN + n0 + n];
    }
    __syncthreads();
    float* out = PT + ((size_t)b * NN + n0) * 61;
    for (int e = tid; e < 61 * 64; e += 256) {
        int n = e / 61, c = e % 61;
        out[e] = tile[c][n];
    }
}

// K1: farthest point sampling. ARITHMETIC FROZEN (r18 PASS).
// r33 VERIFIED (1856-1863 us, VGPR 132 = coords resident): structural floor.
// r35: epilogue also emits out0 (B,3,S) directly from nbuf — deletes the
// k_out0 dispatch. nbuf[s*3+c] stride-3 LDS reads: gcd(3,32)=1 => 32 lanes
// hit 32 distinct banks, conflict-free. Bit-copy.
__device__ __forceinline__ u64 fps_wave_max(u64 key) {
#define FPS_DPP_STAGE(CTRL)                                                   \
    {                                                                         \
        int lo = (int)(unsigned)(key & 0xffffffffull);                        \
        int hi = (int)(unsigned)(key >> 32);                                  \
        int lo2 = __builtin_amdgcn_update_dpp(lo, lo, CTRL, 0xF, 0xF, false); \
        int hi2 = __builtin_amdgcn_update_dpp(hi, hi, CTRL, 0xF, 0xF, false); \
        u64 k2 = ((u64)(unsigned)hi2 << 32) | (unsigned)lo2;                  \
        if (k2 > key) key = k2;                                               \
    }
    FPS_DPP_STAGE(0x121)  // row_ror:1
    FPS_DPP_STAGE(0x122)  // row_ror:2
    FPS_DPP_STAGE(0x124)  // row_ror:4
    FPS_DPP_STAGE(0x128)  // row_ror:8
    FPS_DPP_STAGE(0x142)  // row_bcast15
    FPS_DPP_STAGE(0x143)  // row_bcast31
#undef FPS_DPP_STAGE
    return key;  // lane 63 holds the full wave max
}

__global__ __launch_bounds__(256)
__attribute__((amdgpu_waves_per_eu(1, 1))) void k_fps(
    const float* __restrict__ X, float* __restrict__ NXYZ,
    float* __restrict__ out0) {
    __shared__ float lx[NN], ly[NN], lz[NN];  // 96 KB winner-broadcast cache
    __shared__ float nbuf[SS * 3];            // 24 KB result buffer
    __shared__ u64 wk_[2][4];
    int b = blockIdx.x;
    int tid = threadIdx.x;
    const float* xb = X + (size_t)b * NN * 3;
    float px[32], py[32], pz[32], dist[32];
#pragma unroll
    for (int i = 0; i < 32; ++i) {
        int n = tid + (i << 8);
        px[i] = xb[(size_t)n * 3 + 0];
        py[i] = xb[(size_t)n * 3 + 1];
        pz[i] = xb[(size_t)n * 3 + 2];
        dist[i] = 1e10f;
        lx[n] = px[i]; ly[n] = py[i]; lz[n] = pz[i];
    }
#pragma unroll
    for (int i = 0; i < 32; ++i) {
        asm volatile("" : "+v"(px[i]), "+v"(py[i]), "+v"(pz[i]));
    }
    float c0 = xb[0], c1 = xb[1], c2 = xb[2];
    int lane = tid & 63, wv = tid >> 6;  // wv in 0..3
    __syncthreads();
    for (int t = 0; t < SS; ++t) {
        if (tid == 0) {
            nbuf[t * 3 + 0] = c0; nbuf[t * 3 + 1] = c1; nbuf[t * 3 + 2] = c2;
        }
        float bv0 = -1.0f, bv1 = -1.0f, bv2 = -1.0f, bv3 = -1.0f;
        int bn0 = 0, bn1 = 0, bn2 = 0, bn3 = 0;
#pragma unroll
        for (int i = 0; i < 32; ++i) {
            float dx = __fsub_rn(px[i], c0);
            float dy = __fsub_rn(py[i], c1);
            float dz = __fsub_rn(pz[i], c2);
            float dd = __fadd_rn(__fadd_rn(__fmul_rn(dx, dx), __fmul_rn(dy, dy)),
                                 __fmul_rn(dz, dz));
            float nd = fminf(dist[i], dd);
            dist[i] = nd;
            int n = tid + (i << 8);
            if (i < 8) {
                if (nd > bv0) { bv0 = nd; bn0 = n; }
            } else if (i < 16) {
                if (nd > bv1) { bv1 = nd; bn1 = n; }
            } else if (i < 24) {
                if (nd > bv2) { bv2 = nd; bn2 = n; }
            } else {
                if (nd > bv3) { bv3 = nd; bn3 = n; }
            }
        }
        float bestv = bv0; int bestn = bn0;
        if (bv1 > bestv) { bestv = bv1; bestn = bn1; }
        if (bv2 > bestv) { bestv = bv2; bestn = bn2; }
        if (bv3 > bestv) { bestv = bv3; bestn = bn3; }
        u64 key = ((u64)__float_as_uint(bestv) << 32) | (unsigned)(~bestn);
        key = fps_wave_max(key);
        int pbuf = t & 1;
        if (lane == 63) wk_[pbuf][wv] = key;
        __syncthreads();
        u64 kmax = wk_[pbuf][0];
#pragma unroll
        for (int i = 1; i < 4; ++i) {
            u64 k = wk_[pbuf][i];
            if (k > kmax) kmax = k;
        }
        int kn = (int)(~(unsigned)(kmax & 0xffffffffull));
        c0 = lx[kn]; c1 = ly[kn]; c2 = lz[kn];
    }
    __syncthreads();
    float* ob = NXYZ + (size_t)b * SS * 3;
    for (int e = tid; e < SS * 3; e += 256) ob[e] = nbuf[e];
    // out0 (B,3,S): element e = c*SS+s reads nbuf[s*3+c] (conflict-free).
    float* o0 = out0 + (size_t)b * 3 * SS;
    for (int e = tid; e < 3 * SS; e += 256) {
        int c = e >> 11, s = e & (SS - 1);
        o0[e] = nbuf[s * 3 + c];
    }
}

// K2: ball query. One wave per center. ARITHMETIC FROZEN (r18 PASS).
__global__ __launch_bounds__(256) void k_ballq(const float* __restrict__ X,
                                               const float* __restrict__ NXYZ,
                                               int* __restrict__ GI) {
    int wv = threadIdx.x >> 6, lane = threadIdx.x & 63;
    int gs = blockIdx.x * 4 + wv;           // 0..16383
    int b = gs >> 11;
    const float* xb = X + (size_t)b * NN * 3;
    float c0 = NXYZ[(size_t)gs * 3 + 0];
    float c1 = NXYZ[(size_t)gs * 3 + 1];
    float c2 = NXYZ[(size_t)gs * 3 + 2];
    float A = __fadd_rn(__fadd_rn(__fmul_rn(c0, c0), __fmul_rn(c1, c1)),
                        __fmul_rn(c2, c2));
    const float R2 = 0.04f;
    int cnt = 0, first = 0;
    int* gout = GI + ((size_t)gs << 5);
    for (int r = 0; r < 128 && cnt < 32; ++r) {
        int n = (r << 6) + lane;
        float x0 = xb[(size_t)n * 3 + 0];
        float x1 = xb[(size_t)n * 3 + 1];
        float x2 = xb[(size_t)n * 3 + 2];
        float Bx = __fadd_rn(__fadd_rn(__fmul_rn(x0, x0), __fmul_rn(x1, x1)),
                             __fmul_rn(x2, x2));
        float dot = fmaf(c2, x2, fmaf(c1, x1, __fmul_rn(c0, x0)));  // BLAS asc-FMA
        float t = __fadd_rn(__fmul_rn(-2.0f, dot), Bx);             // += B first
        float sqr = __fadd_rn(t, A);                                // += A second
        bool pred = !(sqr > R2);
        u64 mask = __ballot(pred);
        int rank = cnt + __popcll(mask & ((1ull << lane) - 1ull));
        if (pred && rank < 32) gout[rank] = n;
        if (cnt == 0 && mask) first = (r << 6) + (__ffsll((long long)mask) - 1);
        cnt += __popcll(mask);
    }
    if (cnt < 32 && lane >= cnt && lane < 32) gout[lane] = first;
}

// K3: attention block 1 + maxpool. r34 VERIFIED state (operand sharing,
// b128 GEMMs, PT gather). UNCHANGED (control).
__global__ __launch_bounds__(256) void k_attn1(
    const float* __restrict__ X, const float* __restrict__ NXYZ,
    const int* __restrict__ GI, const float* __restrict__ PT,
    const float* __restrict__ wq, const float* __restrict__ wk,
    const float* __restrict__ wv, const float* __restrict__ wo,
    const float* __restrict__ wp, const float* __restrict__ bp,
    float* __restrict__ FMID) {
    __shared__ float feat[32][68], qS[32][68], kS[32][68], vS[32][68];
    __shared__ float sc[32][36];
    __shared__ float pos[32][3];
    __shared__ int giS[32];
    __shared__ float ctr[3];
    int gs = blockIdx.x;
    int b = gs >> 11;
    int tid = threadIdx.x;
    if (tid < 32) giS[tid] = GI[((size_t)gs << 5) + tid];
    if (tid < 3) ctr[tid] = NXYZ[(size_t)gs * 3 + tid];
    __syncthreads();
    const float* xb = X + (size_t)b * NN * 3;
    const float* ptb = PT + (size_t)b * NN * 61;
    int d = tid & 63, g4 = tid >> 6;
    for (int jj = 0; jj < 8; ++jj) {
        int j = g4 * 8 + jj;
        int idx = giS[j];
        float val;
        if (d < 3) {
            float xv = xb[(size_t)idx * 3 + d];
            pos[j][d] = xv;
            val = __fsub_rn(xv, ctr[d]);
        } else {
            val = ptb[(size_t)idx * 61 + (d - 3)];
        }
        feat[j][d] = val;
    }
    __syncthreads();
    float aq[8], ak[8], av[8];
#pragma unroll
    for (int i = 0; i < 8; ++i) { aq[i] = 0.f; ak[i] = 0.f; av[i] = 0.f; }
    for (int kk4 = 0; kk4 < 16; ++kk4) {
        float4 f4[8];
#pragma unroll
        for (int i = 0; i < 8; ++i)
            f4[i] = *(const float4*)&feat[g4 + 4 * i][kk4 * 4];
#pragma unroll
        for (int j = 0; j < 4; ++j) {
            int kk = kk4 * 4 + j;
            float wqv = wq[kk * 64 + d];
            float wkv = wk[kk * 64 + d];
            float wvv = wv[kk * 64 + d];
#pragma unroll
            for (int i = 0; i < 8; ++i) {
                float f = (j == 0) ? f4[i].x : (j == 1) ? f4[i].y
                                  : (j == 2) ? f4[i].z : f4[i].w;
                aq[i] = fmaf(f, wqv, aq[i]);
                ak[i] = fmaf(f, wkv, ak[i]);
                av[i] = fmaf(f, wvv, av[i]);
            }
        }
    }
    {
        float wp0 = wp[d], wp1 = wp[64 + d], wp2 = wp[128 + d];
        float bpd = bp[d];
#pragma unroll
        for (int i = 0; i < 8; ++i) {
            int j = g4 + 4 * i;
            float pterm = fmaf(pos[j][2], wp2, fmaf(pos[j][1], wp1, pos[j][0] * wp0)) + bpd;
            av[i] += pterm;
            qS[j][d] = aq[i]; kS[j][d] = ak[i]; vS[j][d] = av[i];
        }
    }
    __syncthreads();
    {
        int ci = tid & 31, r0 = tid >> 5;  // r0 in 0..7
        float accv[4] = {0.f, 0.f, 0.f, 0.f};
#pragma unroll
        for (int k4 = 0; k4 < 16; ++k4) {
            float4 kv4 = *(const float4*)&kS[ci][k4 * 4];
#pragma unroll
            for (int rr = 0; rr < 4; ++rr) {
                float4 q4 = *(const float4*)&qS[r0 + 8 * rr][k4 * 4];
                accv[rr] = fmaf(q4.x, kv4.x, accv[rr]);
                accv[rr] = fmaf(q4.y, kv4.y, accv[rr]);
                accv[rr] = fmaf(q4.z, kv4.z, accv[rr]);
                accv[rr] = fmaf(q4.w, kv4.w, accv[rr]);
            }
        }
#pragma unroll
        for (int rr = 0; rr < 4; ++rr) sc[r0 + 8 * rr][ci] = accv[rr] * 0.125f;
    }
    __syncthreads();
    if (tid < 32) {
        float m = -INFINITY;
        for (int i2 = 0; i2 < 32; ++i2) m = fmaxf(m, sc[tid][i2]);
        float sum = 0.f;
        for (int i2 = 0; i2 < 32; ++i2) {
            float e2 = expf(sc[tid][i2] - m);
            sc[tid][i2] = e2; sum += e2;
        }
        float inv = 1.0f / sum;
        for (int i2 = 0; i2 < 32; ++i2) sc[tid][i2] *= inv;
    }
    __syncthreads();
    {
        int dd2 = tid & 63, j0 = tid >> 6;  // j0 in 0..3
        float accv[8];
#pragma unroll
        for (int jj = 0; jj < 8; ++jj) accv[jj] = 0.f;
#pragma unroll
        for (int s4 = 0; s4 < 8; ++s4) {
            float v0 = vS[s4 * 4 + 0][dd2];
            float v1 = vS[s4 * 4 + 1][dd2];
            float v2 = vS[s4 * 4 + 2][dd2];
            float v3 = vS[s4 * 4 + 3][dd2];
#pragma unroll
            for (int jj = 0; jj < 8; ++jj) {
                float4 p4 = *(const float4*)&sc[j0 + 4 * jj][s4 * 4];
                accv[jj] = fmaf(p4.x, v0, accv[jj]);
                accv[jj] = fmaf(p4.y, v1, accv[jj]);
                accv[jj] = fmaf(p4.z, v2, accv[jj]);
                accv[jj] = fmaf(p4.w, v3, accv[jj]);
            }
        }
        __syncthreads();
#pragma unroll
        for (int jj = 0; jj < 8; ++jj) qS[j0 + 4 * jj][dd2] = accv[jj];
    }
    __syncthreads();
    float o[8];
#pragma unroll
    for (int i = 0; i < 8; ++i) o[i] = feat[g4 + 4 * i][d];
    for (int kk4 = 0; kk4 < 16; ++kk4) {
        float4 a4[8];
#pragma unroll
        for (int i = 0; i < 8; ++i)
            a4[i] = *(const float4*)&qS[g4 + 4 * i][kk4 * 4];
#pragma unroll
        for (int j = 0; j < 4; ++j) {
            int kk = kk4 * 4 + j;
            float wov = wo[kk * 64 + d];
#pragma unroll
            for (int i = 0; i < 8; ++i) {
                float a = (j == 0) ? a4[i].x : (j == 1) ? a4[i].y
                                  : (j == 2) ? a4[i].z : a4[i].w;
                o[i] = fmaf(a, wov, o[i]);
            }
        }
    }
    float pm = o[0];
#pragma unroll
    for (int i = 1; i < 8; ++i) pm = fmaxf(pm, o[i]);
    __syncthreads();
    feat[g4][d] = pm;
    __syncthreads();
    if (tid < 64) {
        float mm = fmaxf(fmaxf(feat[0][tid], feat[1][tid]),
                         fmaxf(feat[2][tid], feat[3][tid]));
        FMID[((size_t)gs << 6) + tid] = mm;
    }
}

// K4: q/k/v projections for attention block 2 (rows = B*2048)
__global__ __launch_bounds__(256) void k_qkv2(
    const float* __restrict__ FMID, const float* __restrict__ NXYZ,
    const float* __restrict__ wq, const float* __restrict__ wk,
    const float* __restrict__ wv, const float* __restrict__ wp,
    const float* __restrict__ bpv,
    float* __restrict__ Q2, float* __restrict__ K2, float* __restrict__ V2) {
    __shared__ float f[4][65];
    int tid = threadIdx.x;
    int lr = tid >> 6, d = tid & 63;
    size_t row = (size_t)blockIdx.x * 4 + lr;
    f[lr][d] = FMID[row * 64 + d];
    __syncthreads();
    float aq = 0.f, ak = 0.f, av = 0.f;
    for (int kk = 0; kk < 64; ++kk) {
        float fv = f[lr][kk];
        aq = fmaf(fv, wq[kk * 64 + d], aq);
        ak = fmaf(fv, wk[kk * 64 + d], ak);
        av = fmaf(fv, wv[kk * 64 + d], av);
    }
    float p0 = NXYZ[row * 3], p1 = NXYZ[row * 3 + 1], p2 = NXYZ[row * 3 + 2];
    av += fmaf(p2, wp[128 + d], fmaf(p1, wp[64 + d], p0 * wp[d])) + bpv[d];
    Q2[row * 64 + d] = aq; K2[row * 64 + d] = ak; V2[row * 64 + d] = av;
}

// K5: attention block 2 (r34 state: r29 base + operand sharing).
// r35: wave MAX reduce via DPP (the r26-verified butterfly) — fmaxf is
// exactly associative (no rounding), inputs never NaN, and update_dpp with
// old=own never injects zeros => BIT-EXACT while moving 6 ds_bpermute
// stages to the VALU pipe (1 shfl broadcast remains). SUM reduce unchanged
// (order-sensitive rounding — not touched).
__device__ __forceinline__ float wave_max_f32(float v) {
#define WMF_STAGE(CTRL)                                                       \
    {                                                                         \
        int x = __builtin_amdgcn_update_dpp(__float_as_int(v),                \
                                            __float_as_int(v), CTRL, 0xF,    \
                                            0xF, false);                      \
        v = fmaxf(v, __int_as_float(x));                                      \
    }
    WMF_STAGE(0x121)  // row_ror:1
    WMF_STAGE(0x122)  // row_ror:2
    WMF_STAGE(0x124)  // row_ror:4
    WMF_STAGE(0x128)  // row_ror:8
    WMF_STAGE(0x142)  // row_bcast15
    WMF_STAGE(0x143)  // row_bcast31
#undef WMF_STAGE
    return __shfl(v, 63, 64);  // lane 63 holds the full-wave max
}

__global__ __launch_bounds__(256) void k_attn2(
    const float* __restrict__ Q2, const float* __restrict__ K2,
    const float* __restrict__ V2, const float* __restrict__ FMID,
    const float* __restrict__ wo, float* __restrict__ out1) {
    __shared__ float kT[64][68];  // K tile, 272B rows (16B-aligned)
    __shared__ float vT[64][68];  // V tile, row-major
    __shared__ float qSh[16][64];
    int tid = threadIdx.x;
    int wv = tid >> 6, lane = tid & 63;
    int b = blockIdx.x >> 7, rb = blockIdx.x & 127;
    size_t rbase = (size_t)b * SS + rb * 16;
    {
        int r = tid >> 4, d4 = tid & 15;
        *(float4*)&qSh[r][d4 * 4] =
            *(const float4*)&Q2[(rbase + (size_t)r) * 64 + d4 * 4];
    }
    float acc[4] = {0.f, 0.f, 0.f, 0.f};
    float mr[4] = {-INFINITY, -INFINITY, -INFINITY, -INFINITY};
    float lr[4] = {0.f, 0.f, 0.f, 0.f};
    for (int tt = 0; tt < 32; ++tt) {
        __syncthreads();
        for (int e = tid; e < 1024; e += 256) {
            int r = e >> 4, d4 = e & 15;
            size_t src = ((size_t)b * SS + tt * 64 + r) * 64 + d4 * 4;
            *(float4*)&kT[r][d4 * 4] = *(const float4*)&K2[src];
            *(float4*)&vT[r][d4 * 4] = *(const float4*)&V2[src];
        }
        __syncthreads();
        float sj[4] = {0.f, 0.f, 0.f, 0.f};
#pragma unroll
        for (int d4 = 0; d4 < 16; ++d4) {
            float4 k4 = *(const float4*)&kT[lane][d4 * 4];
#pragma unroll
            for (int rr = 0; rr < 4; ++rr) {
                float4 q4 = *(const float4*)&qSh[wv * 4 + rr][d4 * 4];
                sj[rr] = fmaf(q4.x, k4.x, sj[rr]);
                sj[rr] = fmaf(q4.y, k4.y, sj[rr]);
                sj[rr] = fmaf(q4.z, k4.z, sj[rr]);
                sj[rr] = fmaf(q4.w, k4.w, sj[rr]);
            }
        }
        float pj[4], alpha[4];
#pragma unroll
        for (int rr = 0; rr < 4; ++rr) {
            float s = sj[rr] * 0.125f;
            float tm = wave_max_f32(s);
            float mnew = fmaxf(mr[rr], tm);
            alpha[rr] = expf(mr[rr] - mnew);
            pj[rr] = expf(s - mnew);
            float ps = pj[rr];
#pragma unroll
            for (int off = 32; off > 0; off >>= 1) ps += __shfl_down(ps, (unsigned)off, 64);
            ps = __shfl(ps, 0, 64);
            lr[rr] = lr[rr] * alpha[rr] + ps;
            mr[rr] = mnew;
        }
        float a2[4];
#pragma unroll
        for (int rr = 0; rr < 4; ++rr) a2[rr] = acc[rr] * alpha[rr];
        for (int j = 0; j < 64; ++j) {
            float v = vT[j][lane];
#pragma unroll
            for (int rr = 0; rr < 4; ++rr) {
                float pb2 = __shfl(pj[rr], j, 64);
                a2[rr] = fmaf(pb2, v, a2[rr]);
            }
        }
#pragma unroll
        for (int rr = 0; rr < 4; ++rr) acc[rr] = a2[rr];
    }
#pragma unroll
    for (int rr = 0; rr < 4; ++rr) {
        int lrow = wv * 4 + rr;
        size_t row = rbase + lrow;
        float avl = acc[rr] / lr[rr];
        float o = FMID[row * 64 + lane];
        for (int kk = 0; kk < 64; ++kk) {
            float avk = __shfl(avl, kk, 64);
            o = fmaf(avk, wo[kk * 64 + lane], o);
        }
        out1[((size_t)b * 64 + lane) * SS + (size_t)(rb * 16 + lrow)] = o;
    }
}

extern "C" void kernel_launch(void* const* d_in, const int* in_sizes, int n_in,
                              void* d_out, int out_size, void* d_ws, size_t ws_size,
                              hipStream_t stream) {
    const float* xyz = (const float*)d_in[0];
    const float* pts = (const float*)d_in[1];
    const float* w1q = (const float*)d_in[2];
    const float* w1k = (const float*)d_in[3];
    const float* w1v = (const float*)d_in[4];
    const float* w1o = (const float*)d_in[5];
    const float* w1p = (const float*)d_in[6];
    const float* b1p = (const float*)d_in[7];
    const float* w2q = (const float*)d_in[8];
    const float* w2k = (const float*)d_in[9];
    const float* w2v = (const float*)d_in[10];
    const float* w2o = (const float*)d_in[11];
    const float* w2p = (const float*)d_in[12];
    const float* b2p = (const float*)d_in[13];

    float* X = (float*)d_ws;                               // B*N*3
    float* NXYZ = X + (size_t)BB * NN * 3;                 // B*S*3
    int* GI = (int*)(NXYZ + (size_t)BB * SS * 3);          // B*S*32
    float* FMID = (float*)(GI + (size_t)BB * SS * 32);     // B*S*64
    float* Q2 = FMID + (size_t)BB * SS * 64;
    float* K2 = Q2 + (size_t)BB * SS * 64;
    float* V2 = K2 + (size_t)BB * SS * 64;
    float* PTws = V2 + (size_t)BB * SS * 64;               // B*N*61 (16 MB)

    float* out0 = (float*)d_out;
    float* out1 = out0 + (size_t)BB * 3 * SS;

    k_transpose<<<768, 256, 0, stream>>>(xyz, X);
    k_transP<<<BB * 128, 256, 0, stream>>>(pts, PTws);
    k_fps<<<BB, 256, 0, stream>>>(X, NXYZ, out0);
    k_ballq<<<4096, 256, 0, stream>>>(X, NXYZ, GI);
    k_attn1<<<16384, 256, 0, stream>>>(X, NXYZ, GI, PTws, w1q, w1k, w1v, w1o,
                                       w1p, b1p, FMID);
    k_qkv2<<<4096, 256, 0, stream>>>(FMID, NXYZ, w2q, w2k, w2v, w2p, b2p,
                                     Q2, K2, V2);
    k_attn2<<<1024, 256, 0, stream>>>(Q2, K2, V2, FMID, w2o, out1);
}